// Round 13
// baseline (166.813 us; speedup 1.0000x reference)
//
#include <hip/hip_runtime.h>

typedef __bf16 bf16;
typedef __bf16 bf16x8 __attribute__((ext_vector_type(8)));
typedef __bf16 bf16x4 __attribute__((ext_vector_type(4)));
typedef float f32x4 __attribute__((ext_vector_type(4)));

constexpr int D = 2048, H = 16, DPH = 128, DR = 64, DC_KV = 16, DC_Q = 512;
constexpr int QHD = 192, MEG = 256, B = 2, S = 2048;
constexpr int T = B * S;
constexpr int NDNP = 640;   // fused down-proj width (512 q + 80 kv), padded to x128
constexpr int NQX = 1280;   // q gemm width: 256 absorbed qc + 1024 rope
constexpr float EPS = 1e-7f;
constexpr float KSC = 0.104124247f;  // (1/sqrt(192)) * log2(e), folded into Qp

static __device__ __forceinline__ bf16x8 zero8() {
  bf16x8 v;
#pragma unroll
  for (int j = 0; j < 8; j++) v[j] = (bf16)0.f;
  return v;
}

static __device__ __forceinline__ void gload_lds16(const bf16* g, bf16* l) {
  __builtin_amdgcn_global_load_lds(
      (const __attribute__((address_space(1))) unsigned int*)g,
      (__attribute__((address_space(3))) unsigned int*)l, 16, 0, 0);
}

#define LGWAIT0 do { asm volatile("s_waitcnt lgkmcnt(0)" ::: "memory"); __builtin_amdgcn_sched_barrier(0); } while (0)
#define VMWAIT0 do { asm volatile("s_waitcnt vmcnt(0)" ::: "memory"); __builtin_amdgcn_sched_barrier(0); } while (0)

// ---------------- rope table (f64 precision, once) ----------------
__global__ void rope_table_kernel(float* __restrict__ cos_t, float* __restrict__ sin_t) {
  int i = blockIdx.x * 64 + threadIdx.x;  // over S*32
  int pos = i >> 5, j = i & 31;
  double invf = pow(10000.0, -(double)(2 * j) / 64.0);
  double a = (double)pos * invf;
  cos_t[i] = (float)cos(a);
  sin_t[i] = (float)sin(a);
}

// ---------------- zero fill (bf16, n multiple of 8) ----------------
__global__ void zero_bf16_kernel(bf16* __restrict__ p, int n) {
  int i = (blockIdx.x * 256 + threadIdx.x) * 8;
  if (i < n) *reinterpret_cast<bf16x8*>(p + i) = zero8();
}

// ---------------- transpose + cast: out[n][k] = (bf16) in[k][n], in is K x N f32 ----------------
__global__ __launch_bounds__(256) void transpose_cast_kernel(
    const float* __restrict__ in, bf16* __restrict__ out, int K, int N, int ldo) {
  __shared__ float tile[32][33];
  int k0 = blockIdx.y * 32, n0 = blockIdx.x * 32;
  int tid = threadIdx.x;
#pragma unroll
  for (int e = tid; e < 1024; e += 256) {
    int i = e >> 5, j = e & 31;
    int k = k0 + i, n = n0 + j;
    tile[i][j] = (k < K && n < N) ? in[(size_t)k * N + n] : 0.f;
  }
  __syncthreads();
#pragma unroll
  for (int e = tid; e < 1024; e += 256) {
    int jj = e >> 5, ii = e & 31;
    int n = n0 + jj, k = k0 + ii;
    if (k < K && n < N) out[(size_t)n * ldo + k] = (bf16)tile[ii][jj];
  }
}

// ---------------- W2T[d][h*16+c] = sum_v Wkv_up[c][h*256+128+v] * Wout[h*128+v][d] ----------------
__global__ __launch_bounds__(128) void prep_w2_kernel(
    const float* __restrict__ Wkv_up, const float* __restrict__ Wout,
    bf16* __restrict__ W2T) {
  __shared__ float wv[128][16];   // [v][c]
  int h = blockIdx.y, d0 = blockIdx.x * 128;
  int tid = threadIdx.x;
#pragma unroll
  for (int e = tid; e < 2048; e += 128) {
    int v = e >> 4, c = e & 15;
    wv[v][c] = Wkv_up[(size_t)c * (H * MEG) + h * MEG + 128 + v];
  }
  __syncthreads();
  int d = d0 + tid;
  float acc[16] = {};
  for (int v = 0; v < 128; v++) {
    float wo = Wout[(size_t)(h * 128 + v) * D + d];
    float4 a0 = *reinterpret_cast<const float4*>(&wv[v][0]);
    float4 a1 = *reinterpret_cast<const float4*>(&wv[v][4]);
    float4 a2 = *reinterpret_cast<const float4*>(&wv[v][8]);
    float4 a3 = *reinterpret_cast<const float4*>(&wv[v][12]);
    acc[0] += a0.x * wo;  acc[1] += a0.y * wo;  acc[2] += a0.z * wo;  acc[3] += a0.w * wo;
    acc[4] += a1.x * wo;  acc[5] += a1.y * wo;  acc[6] += a1.z * wo;  acc[7] += a1.w * wo;
    acc[8] += a2.x * wo;  acc[9] += a2.y * wo;  acc[10] += a2.z * wo; acc[11] += a2.w * wo;
    acc[12] += a3.x * wo; acc[13] += a3.y * wo; acc[14] += a3.z * wo; acc[15] += a3.w * wo;
  }
  bf16x8 o0, o1;
#pragma unroll
  for (int c = 0; c < 8; c++) { o0[c] = (bf16)acc[c]; o1[c] = (bf16)acc[8 + c]; }
  *reinterpret_cast<bf16x8*>(&W2T[(size_t)d * 256 + h * 16]) = o0;
  *reinterpret_cast<bf16x8*>(&W2T[(size_t)d * 256 + h * 16 + 8]) = o1;
}

// ---------------- WqxT[h*16+c][k] = sum_v Wq_up[k][h*192+v] * Wkv_up[c][h*256+v] ----------------
__global__ __launch_bounds__(128) void prep_w3_kernel(
    const float* __restrict__ Wq_up, const float* __restrict__ Wkv_up,
    bf16* __restrict__ WqxT) {
  __shared__ float wk[128][16];   // [v][c]
  int h = blockIdx.y, k0 = blockIdx.x * 128;
  int tid = threadIdx.x;
#pragma unroll
  for (int e = tid; e < 2048; e += 128) {
    int v = e >> 4, c = e & 15;
    wk[v][c] = Wkv_up[(size_t)c * (H * MEG) + h * MEG + v];
  }
  __syncthreads();
  int k = k0 + tid;
  float acc[16] = {};
  for (int v = 0; v < 128; v++) {
    float wq = Wq_up[(size_t)k * (H * QHD) + h * QHD + v];
    float4 a0 = *reinterpret_cast<const float4*>(&wk[v][0]);
    float4 a1 = *reinterpret_cast<const float4*>(&wk[v][4]);
    float4 a2 = *reinterpret_cast<const float4*>(&wk[v][8]);
    float4 a3 = *reinterpret_cast<const float4*>(&wk[v][12]);
    acc[0] += a0.x * wq;  acc[1] += a0.y * wq;  acc[2] += a0.z * wq;  acc[3] += a0.w * wq;
    acc[4] += a1.x * wq;  acc[5] += a1.y * wq;  acc[6] += a1.z * wq;  acc[7] += a1.w * wq;
    acc[8] += a2.x * wq;  acc[9] += a2.y * wq;  acc[10] += a2.z * wq; acc[11] += a2.w * wq;
    acc[12] += a3.x * wq; acc[13] += a3.y * wq; acc[14] += a3.z * wq; acc[15] += a3.w * wq;
  }
#pragma unroll
  for (int c = 0; c < 16; c++)
    WqxT[(size_t)(h * 16 + c) * DC_Q + k] = (bf16)acc[c];
}

// ---------------- WqxT[256 + h*64 + j][k] = Wq_up[k][h*192+128+j] (rope cols) ----------------
__global__ __launch_bounds__(256) void prep_wrope_kernel(
    const float* __restrict__ Wq_up, bf16* __restrict__ WqxT) {
  __shared__ float tile[64][65];
  int h = blockIdx.y, k0 = blockIdx.x * 64;
  int tid = threadIdx.x;
#pragma unroll
  for (int p = 0; p < 16; p++) {
    int kk = p * 4 + (tid >> 6), j = tid & 63;
    tile[kk][j] = Wq_up[(size_t)(k0 + kk) * (H * QHD) + h * QHD + 128 + j];
  }
  __syncthreads();
#pragma unroll
  for (int p = 0; p < 16; p++) {
    int n = p * 4 + (tid >> 6), k = tid & 63;
    WqxT[(size_t)(256 + h * 64 + n) * DC_Q + k0 + k] = (bf16)tile[k][n];
  }
}

// ---------------- rms scale only: rsc[t] = rsqrt(mean(cqkv[t][0..511]^2) + eps) ----------------
__global__ __launch_bounds__(256) void rms_scale_kernel(
    const float* __restrict__ cqkv, float* __restrict__ rsc) {
  int wid = threadIdx.x >> 6, lane = threadIdx.x & 63;
  int t = blockIdx.x * 4 + wid;
  const float* x = cqkv + (size_t)t * NDNP;
  float4 v0 = *reinterpret_cast<const float4*>(x + lane * 8);
  float4 v1 = *reinterpret_cast<const float4*>(x + lane * 8 + 4);
  float ss = v0.x * v0.x + v0.y * v0.y + v0.z * v0.z + v0.w * v0.w +
             v1.x * v1.x + v1.y * v1.y + v1.z * v1.z + v1.w * v1.w;
#pragma unroll
  for (int off = 32; off; off >>= 1) ss += __shfl_xor(ss, off);
  if (lane == 0) rsc[t] = rsqrtf(ss / (float)DC_Q + EPS);
}

// ---------------- kv prep: Kc row = [rope64 | c16 | zero pad..128]; cT[c][s] = c_kv^T ----------------
__global__ __launch_bounds__(64) void kv_prep_kernel(
    const float* __restrict__ cqkv, const float* __restrict__ kvw,
    const int* __restrict__ pos_ids,
    const float* __restrict__ cos_t, const float* __restrict__ sin_t,
    bf16* __restrict__ KcG, bf16* __restrict__ cTG) {
  int t = blockIdx.x;
  int lane = threadIdx.x;
  int b = t >> 11, s = t & (S - 1);
  const float* x = cqkv + (size_t)t * NDNP + DC_Q;
  float v = (lane < 16) ? x[lane] : 0.f;
  float ss = v * v;
#pragma unroll
  for (int off = 1; off < 16; off <<= 1) ss += __shfl_xor(ss, off);
  float r = rsqrtf(ss / 16.f + EPS);
  bf16* krow = KcG + ((size_t)t << 7);
  if (lane < 16) {
    bf16 cn = (bf16)(v * r * kvw[lane]);
    krow[64 + lane] = cn;
    cTG[(size_t)(b * 16 + lane) * S + s] = cn;
  } else {
    krow[64 + lane] = (bf16)0.f;   // dims 80..127 zero
  }
  if (lane < 32) {
    int j = lane;
    int pos = pos_ids[t];
    float cf = cos_t[pos * 32 + j], sf = sin_t[pos * 32 + j];
    float x0 = x[16 + 2 * j], x1 = x[16 + 2 * j + 1];
    krow[j]      = (bf16)(x0 * cf - x1 * sf);
    krow[32 + j] = (bf16)(x1 * cf + x0 * sf);
  }
}

// ---------------- build Qp (B*H, S, 96) = KSC*[rope64 | qc16 | zero16] from qx ----------------
__global__ __launch_bounds__(256) void build_q_kernel(
    const bf16* __restrict__ qx, const int* __restrict__ pos_ids,
    const float* __restrict__ cos_t, const float* __restrict__ sin_t,
    bf16* __restrict__ Qp) {
  int t = blockIdx.x;
  int b = t >> 11, s = t & (S - 1);
  int tid = threadIdx.x;
  int pos = pos_ids[t];
  const bf16* qr = qx + (size_t)t * NQX;
#pragma unroll
  for (int rep = 0; rep < 2; rep++) {
    int item = rep * 256 + tid;
    int h = item >> 5, j = item & 31;
    float cf = cos_t[pos * 32 + j], sf = sin_t[pos * 32 + j];
    float x0 = (float)qr[256 + h * 64 + 2 * j], x1 = (float)qr[256 + h * 64 + 2 * j + 1];
    bf16* qrow = Qp + (size_t)((b * 16 + h) * 2048 + s) * 96;
    qrow[j]      = (bf16)((x0 * cf - x1 * sf) * KSC);
    qrow[32 + j] = (bf16)((x1 * cf + x0 * sf) * KSC);
  }
  {
    int h = tid >> 4, c = tid & 15;
    bf16* qrow = Qp + (size_t)((b * 16 + h) * 2048 + s) * 96;
    qrow[64 + c] = (bf16)((float)qr[h * 16 + c] * KSC);
    qrow[80 + c] = (bf16)0.f;
  }
}

// ---------------- bf16 MFMA GEMM with fused A-source modes ----------------
// AMODE 0: A is bf16[M][K], dbuf global_load_lds (both A and B).
// AMODE 1: A is f32[M][lda], reg-staged + cvt bf16 (single-buffer As, attn-style).
// AMODE 2: AMODE1 plus rmsnorm fusion: a = f32val * rsc[row] * wnorm[k].
template <typename OutT, int AMODE>
__global__ __launch_bounds__(256) void gemm_bt_kernel(
    const void* __restrict__ Asrc, const bf16* __restrict__ Bt,
    OutT* __restrict__ C, int M, int N, int K, int lda,
    const float* __restrict__ rsc, const float* __restrict__ wnorm) {
  __shared__ bf16 As[2][128 * 64];
  __shared__ bf16 Bs[2][128 * 64];
  int tid = threadIdx.x;
  int wid = tid >> 6, lane = tid & 63;
  int g = lane >> 4, c = lane & 15;
  int wr = wid >> 1, wc = wid & 1;
  int nbx = gridDim.x;
  int lin = blockIdx.y * nbx + blockIdx.x;
  int cpx = (nbx * gridDim.y) >> 3;
  int swz = (lin & 7) * cpx + (lin >> 3);
  int m0 = (swz / nbx) * 128, n0 = (swz % nbx) * 128;
  int lrow8 = lane >> 3, lslot = lane & 7;

  auto stage_b = [&](int kt, int buf) {
    int k0 = kt << 6;
#pragma unroll
    for (int r = 0; r < 4; r++) {
      int row = (r * 4 + wid) * 8 + lrow8;
      int sslot = lslot ^ (row & 7);
      gload_lds16(Bt + (size_t)(n0 + row) * K + k0 + sslot * 8, &Bs[buf][row * 64 + lslot * 8]);
    }
  };
  auto stage_a0 = [&](int kt, int buf) {
    const bf16* A = (const bf16*)Asrc;
    int k0 = kt << 6;
#pragma unroll
    for (int r = 0; r < 4; r++) {
      int row = (r * 4 + wid) * 8 + lrow8;
      int sslot = lslot ^ (row & 7);
      gload_lds16(A + (size_t)(m0 + row) * K + k0 + sslot * 8, &As[buf][row * 64 + lslot * 8]);
    }
  };

  // reg-staged A path (AMODE 1/2): thread covers rows j*32+(tid>>3), cols (tid&7)*8..+7
  int j4 = tid >> 3, s8 = tid & 7;
  float4 areg[8];
  float4 wr0 = {1.f, 1.f, 1.f, 1.f}, wr1 = {1.f, 1.f, 1.f, 1.f};
  float rreg[4] = {1.f, 1.f, 1.f, 1.f};
  auto load_a = [&](int kt) {
    const float* Af = (const float*)Asrc;
    int k0 = kt << 6;
#pragma unroll
    for (int j = 0; j < 4; j++) {
      int row = j * 32 + j4;
      const float* src = Af + (size_t)(m0 + row) * lda + k0 + s8 * 8;
      areg[2 * j]     = *reinterpret_cast<const float4*>(src);
      areg[2 * j + 1] = *reinterpret_cast<const float4*>(src + 4);
    }
    if constexpr (AMODE == 2) {
      wr0 = *reinterpret_cast<const float4*>(wnorm + k0 + s8 * 8);
      wr1 = *reinterpret_cast<const float4*>(wnorm + k0 + s8 * 8 + 4);
    }
  };
  auto write_a = [&]() {
#pragma unroll
    for (int j = 0; j < 4; j++) {
      int row = j * 32 + j4;
      float sc = rreg[j];
      bf16x8 v;
      v[0] = (bf16)(areg[2 * j].x * sc * wr0.x);
      v[1] = (bf16)(areg[2 * j].y * sc * wr0.y);
      v[2] = (bf16)(areg[2 * j].z * sc * wr0.z);
      v[3] = (bf16)(areg[2 * j].w * sc * wr0.w);
      v[4] = (bf16)(areg[2 * j + 1].x * sc * wr1.x);
      v[5] = (bf16)(areg[2 * j + 1].y * sc * wr1.y);
      v[6] = (bf16)(areg[2 * j + 1].z * sc * wr1.z);
      v[7] = (bf16)(areg[2 * j + 1].w * sc * wr1.w);
      *reinterpret_cast<bf16x8*>(&As[0][row * 64 + (s8 ^ (row & 7)) * 8]) = v;
    }
  };

  f32x4 acc[4][4] = {};
  int nk = K >> 6;

  if constexpr (AMODE == 0) {
    stage_a0(0, 0);
    stage_b(0, 0);
    __builtin_amdgcn_sched_barrier(0);
    for (int kt = 0; kt < nk; kt++) {
      int cur = kt & 1;
      __builtin_amdgcn_s_barrier();
      __builtin_amdgcn_sched_barrier(0);
      if (kt + 1 < nk) {
        stage_a0(kt + 1, cur ^ 1);
        stage_b(kt + 1, cur ^ 1);
        asm volatile("s_waitcnt vmcnt(8)" ::: "memory");
      } else {
        asm volatile("s_waitcnt vmcnt(0)" ::: "memory");
      }
      __builtin_amdgcn_sched_barrier(0);
      __builtin_amdgcn_s_barrier();
      __builtin_amdgcn_sched_barrier(0);
#pragma unroll
      for (int kk = 0; kk < 2; kk++) {
        bf16x8 af[4], bfr[4];
#pragma unroll
        for (int mi = 0; mi < 4; mi++) {
          int row = wr * 64 + mi * 16 + c;
          int sl = (kk * 4 + g) ^ (row & 7);
          af[mi] = *reinterpret_cast<const bf16x8*>(&As[cur][row * 64 + sl * 8]);
        }
#pragma unroll
        for (int ni = 0; ni < 4; ni++) {
          int row = wc * 64 + ni * 16 + c;
          int sl = (kk * 4 + g) ^ (row & 7);
          bfr[ni] = *reinterpret_cast<const bf16x8*>(&Bs[cur][row * 64 + sl * 8]);
        }
#pragma unroll
        for (int mi = 0; mi < 4; mi++)
#pragma unroll
          for (int ni = 0; ni < 4; ni++)
            acc[mi][ni] = __builtin_amdgcn_mfma_f32_16x16x32_bf16(af[mi], bfr[ni], acc[mi][ni], 0, 0, 0);
      }
    }
  } else {
    if constexpr (AMODE == 2) {
#pragma unroll
      for (int j = 0; j < 4; j++) rreg[j] = rsc[m0 + j * 32 + j4];
    }
    stage_b(0, 0);
    __builtin_amdgcn_sched_barrier(0);
    load_a(0);
    VMWAIT0;                        // A0 regs (+rsc) + B0 LDS landed
    write_a();
    if (nk > 1) {
      stage_b(1, 1);
      __builtin_amdgcn_sched_barrier(0);
      load_a(1);
    }
    LGWAIT0;
    __builtin_amdgcn_s_barrier();   // As tile0 + Bs[0] ready
    __builtin_amdgcn_sched_barrier(0);
    for (int kt = 0; kt < nk; kt++) {
      int cur = kt & 1;
#pragma unroll
      for (int kk = 0; kk < 2; kk++) {
        bf16x8 af[4], bfr[4];
#pragma unroll
        for (int mi = 0; mi < 4; mi++) {
          int row = wr * 64 + mi * 16 + c;
          int sl = (kk * 4 + g) ^ (row & 7);
          af[mi] = *reinterpret_cast<const bf16x8*>(&As[0][row * 64 + sl * 8]);
        }
#pragma unroll
        for (int ni = 0; ni < 4; ni++) {
          int row = wc * 64 + ni * 16 + c;
          int sl = (kk * 4 + g) ^ (row & 7);
          bfr[ni] = *reinterpret_cast<const bf16x8*>(&Bs[cur][row * 64 + sl * 8]);
        }
#pragma unroll
        for (int mi = 0; mi < 4; mi++)
#pragma unroll
          for (int ni = 0; ni < 4; ni++)
            acc[mi][ni] = __builtin_amdgcn_mfma_f32_16x16x32_bf16(af[mi], bfr[ni], acc[mi][ni], 0, 0, 0);
      }
      if (kt + 1 < nk) {
        __builtin_amdgcn_s_barrier();   // A: all waves done reading As & Bs[cur]
        __builtin_amdgcn_sched_barrier(0);
        VMWAIT0;                        // A(kt+1) regs + B(kt+1) LDS landed
        write_a();
        if (kt + 2 < nk) {
          stage_b(kt + 2, cur);
          __builtin_amdgcn_sched_barrier(0);
          load_a(kt + 2);
        }
        LGWAIT0;
        __builtin_amdgcn_s_barrier();   // B: As tile kt+1 visible
        __builtin_amdgcn_sched_barrier(0);
      }
    }
  }
#pragma unroll
  for (int mi = 0; mi < 4; mi++)
#pragma unroll
    for (int ni = 0; ni < 4; ni++)
#pragma unroll
      for (int r = 0; r < 4; r++) {
        int row = m0 + wr * 64 + mi * 16 + g * 4 + r;
        int col = n0 + wc * 64 + ni * 16 + c;
        C[(size_t)row * N + col] = (OutT)acc[mi][ni][r];
      }
}

// ---------------- absorbed flash attention, single-Kls reg-staged, 2 blocks/CU ----------------
__global__ __launch_bounds__(512, 4) void attn_kernel(
    const bf16* __restrict__ Qp, const bf16* __restrict__ KcG,
    const bf16* __restrict__ cTG, bf16* __restrict__ OC) {
  __shared__ bf16 Kls[128 * 128];     // 32KB: entry (key,e): e holds slot e^(key>>3)
  __shared__ bf16 Cls[2][16 * 128];   // 4KB x2: entry (c,e): e holds slot e^c
  __shared__ bf16 Pls[8][16 * 128];   // 4KB per wave

  int lin = blockIdx.x;               // 0..511
  int v = lin >> 8, u = lin & 255;
  int qt = v ? (u >> 1) : (127 - (u >> 1));   // anti-correlated heavy/light halves
  int hg = u & 1, b = v;
  int q0 = qt * 16;
  int nt = qt / 8 + 1;
  int tid = threadIdx.x;
  int w = tid >> 6, lane = tid & 63;
  int g = lane >> 4, cc = lane & 15;
  int h = hg * 8 + w;
  char* pbase = reinterpret_cast<char*>(&Pls[w][0]);

  bf16x8 kst[4];
  auto load_k = [&](int k0) {
#pragma unroll
    for (int i = 0; i < 4; i++) {
      int id = w * 4 + i;
      int key = id * 4 + (lane >> 4);
      int sg = (lane & 15) ^ ((id >> 1) & 15);
      kst[i] = *reinterpret_cast<const bf16x8*>(
          KcG + (((size_t)(b * S + k0 + key)) << 7) + sg * 8);
    }
  };
  auto write_k = [&]() {
#pragma unroll
    for (int i = 0; i < 4; i++) {
      int id = w * 4 + i;
      *reinterpret_cast<bf16x8*>(&Kls[(id * 64 + lane) * 8]) = kst[i];
    }
  };
  auto stage_c = [&](int k0, int buf) {
    if (w >= 4) {
      int c = (w - 4) * 4 + (lane >> 4);
      int sg = (lane & 15) ^ c;
      gload_lds16(cTG + (size_t)(b * 16 + c) * S + k0 + sg * 8,
                  &Cls[buf][(w - 4) * 512]);
    }
  };

  // ---- Q fragments (pre-scaled by KSC at build time) ----
  bf16x8 aq[3];
  const bf16* qp = Qp + (size_t)((b * 16 + h) * 2048 + q0 + cc) * 96;
#pragma unroll
  for (int kk = 0; kk < 3; kk++)
    aq[kk] = *reinterpret_cast<const bf16x8*>(qp + kk * 32 + g * 8);

  // ---- prologue ----
  stage_c(0, 0);
  __builtin_amdgcn_sched_barrier(0);
  load_k(0);
  VMWAIT0;                        // K0 regs + C0 landed
  write_k();
  if (nt > 1) {
    stage_c(128, 1);
    __builtin_amdgcn_sched_barrier(0);
    load_k(128);
  }
  LGWAIT0;
  __builtin_amdgcn_s_barrier();   // Kls tile0 + Cls[0] ready
  __builtin_amdgcn_sched_barrier(0);

  bf16x8 ones;
#pragma unroll
  for (int j = 0; j < 8; j++) ones[j] = (bf16)1.f;

  f32x4 oc = {}, ls = {};

#pragma unroll 1
  for (int kt = 0; kt < nt; kt++) {
    int cur = kt & 1;
    int k0 = kt * 128;
    // ---- QK^T over 96 dims (3 K-steps) x 128 keys; col cc of MFMA ntb = key cc*8+ntb ----
    f32x4 sacc[8] = {};
    __builtin_amdgcn_s_setprio(1);
#pragma unroll
    for (int kk = 0; kk < 3; kk++)
#pragma unroll
      for (int ntb = 0; ntb < 8; ntb++) {
        int key = cc * 8 + ntb;
        bf16x8 bk = *reinterpret_cast<const bf16x8*>(
            &Kls[(key * 16 + ((kk * 4 + g) ^ cc)) * 8]);
        sacc[ntb] = __builtin_amdgcn_mfma_f32_16x16x32_bf16(aq[kk], bk, sacc[ntb], 0, 0, 0);
      }
    __builtin_amdgcn_s_setprio(0);

    // ---- max-free softmax: p = exp2(s') (s' pre-scaled); masked -> exp2(-1e30) = 0 ----
    bool diag = (kt == nt - 1);
#pragma unroll
    for (int r = 0; r < 4; r++) {
      bf16x8 pk;
#pragma unroll
      for (int ntb = 0; ntb < 8; ntb++) {
        float x = sacc[ntb][r];
        if (diag) {
          int qr = q0 + g * 4 + r, kc = k0 + cc * 8 + ntb;
          if (kc > qr) x = -1e30f;
        }
        pk[ntb] = (bf16)__builtin_amdgcn_exp2f(x);
      }
      int q = g * 4 + r;
      *reinterpret_cast<bf16x8*>(pbase + (q * 16 + (cc ^ (q & 7))) * 16) = pk;
    }
    LGWAIT0;
    // ---- PV + row-sum via ones-MFMA (matrix pipe does the reduction) ----
    __builtin_amdgcn_s_setprio(1);
#pragma unroll
    for (int kk2 = 0; kk2 < 4; kk2++) {
      bf16x8 pa = *reinterpret_cast<const bf16x8*>(
          pbase + (cc * 16 + ((kk2 * 4 + g) ^ (cc & 7))) * 16);
      bf16x8 bv = *reinterpret_cast<const bf16x8*>(
          &Cls[cur][(cc * 16 + ((kk2 * 4 + g) ^ cc)) * 8]);
      oc = __builtin_amdgcn_mfma_f32_16x16x32_bf16(pa, bv, oc, 0, 0, 0);
      ls = __builtin_amdgcn_mfma_f32_16x16x32_bf16(pa, ones, ls, 0, 0, 0);
    }
    __builtin_amdgcn_s_setprio(0);

    if (kt + 1 < nt) {
      __builtin_amdgcn_s_barrier();     // A: all waves done reading Kls & Cls[cur]
      __builtin_amdgcn_sched_barrier(0);
      VMWAIT0;                          // K(kt+1) regs + C(kt+1) landed (issued 1 tile ago)
      write_k();                        // K(kt+1) -> Kls
      if (kt + 2 < nt) {
        stage_c((kt + 2) * 128, cur);   // C(kt+2) -> Cls[cur] (free after barrier A)
        __builtin_amdgcn_sched_barrier(0);
        load_k((kt + 2) * 128);
      }
      LGWAIT0;                          // my ds_writes drained
      __builtin_amdgcn_s_barrier();     // B: Kls tile kt+1 visible
      __builtin_amdgcn_sched_barrier(0);
    }
  }

  // ---- epilogue ----
#pragma unroll
  for (int r = 0; r < 4; r++) {
    size_t t = (size_t)b * S + q0 + g * 4 + r;
    OC[t * 256 + h * 16 + cc] = (bf16)(oc[r] / ls[r]);
  }
}

// ---------------- host ----------------
extern "C" void kernel_launch(void* const* d_in, const int* in_sizes, int n_in,
                              void* d_out, int out_size, void* d_ws, size_t ws_size,
                              hipStream_t stream) {
  const float* inputs    = (const float*)d_in[0];
  const int*   pos_ids   = (const int*)d_in[1];
  const float* Wq_down   = (const float*)d_in[3];
  const float* q_norm_w  = (const float*)d_in[4];
  const float* Wq_up     = (const float*)d_in[5];
  const float* Wkv_down  = (const float*)d_in[6];
  const float* kv_norm_w = (const float*)d_in[7];
  const float* Wkv_up    = (const float*)d_in[8];
  const float* Wout      = (const float*)d_in[9];
  float* out = (float*)d_out;

  char* ws = (char*)d_ws;
  size_t off = 0;
  auto alloc = [&](size_t bytes) -> void* {
    void* p = ws + off;
    off += (bytes + 255) & ~(size_t)255;
    return p;
  };

  bf16*  WdT   = (bf16*)alloc((size_t)NDNP * D * 2);        // fused down-proj weights^T
  bf16*  WqxT  = (bf16*)alloc((size_t)NQX * DC_Q * 2);      // [absorbed qc 256 | rope 1024] x 512
  bf16*  W2T   = (bf16*)alloc((size_t)D * 256 * 2);         // absorbed out-proj weights^T
  float* cqkv  = (float*)alloc((size_t)T * NDNP * 4);
  float* rsc   = (float*)alloc((size_t)T * 4);              // rmsnorm scales for q path
  bf16*  qx    = (bf16*)alloc((size_t)T * NQX * 2);         // q gemm output
  bf16*  KcG   = (bf16*)alloc((size_t)T * 128 * 2);         // [rope64|c16|pad] per token
  bf16*  cTG   = (bf16*)alloc((size_t)B * 16 * S * 2);      // c_kv^T per batch
  bf16*  Qp    = (bf16*)alloc((size_t)B * H * S * 96 * 2);  // absorbed Q (pre-scaled)
  bf16*  OC    = (bf16*)alloc((size_t)T * H * 16 * 2);      // attention out in c-space
  float* cos_t = (float*)alloc((size_t)S * 32 * 4);
  float* sin_t = (float*)alloc((size_t)S * 32 * 4);

  rope_table_kernel<<<S * 32 / 64, 64, 0, stream>>>(cos_t, sin_t);
  zero_bf16_kernel<<<(NDNP * D / 8 + 255) / 256, 256, 0, stream>>>(WdT, NDNP * D);
  transpose_cast_kernel<<<dim3((DC_Q + 31) / 32, (D + 31) / 32), 256, 0, stream>>>(Wq_down, WdT, D, DC_Q, D);
  transpose_cast_kernel<<<dim3((80 + 31) / 32, (D + 31) / 32), 256, 0, stream>>>(Wkv_down, WdT + (size_t)DC_Q * D, D, 80, D);
  prep_w3_kernel<<<dim3(4, 16), 128, 0, stream>>>(Wq_up, Wkv_up, WqxT);
  prep_wrope_kernel<<<dim3(8, 16), 256, 0, stream>>>(Wq_up, WqxT);
  prep_w2_kernel<<<dim3(16, 16), 128, 0, stream>>>(Wkv_up, Wout, W2T);

  // down-proj: A = f32 inputs (cast fused into staging)
  gemm_bt_kernel<float, 1><<<dim3(NDNP / 128, T / 128), 256, 0, stream>>>(
      inputs, WdT, cqkv, T, NDNP, D, D, nullptr, nullptr);
  rms_scale_kernel<<<T / 4, 256, 0, stream>>>(cqkv, rsc);
  kv_prep_kernel<<<T, 64, 0, stream>>>(cqkv, kv_norm_w, pos_ids, cos_t, sin_t, KcG, cTG);
  // q-gemm: A = cqkv f32 with fused rmsnorm scale (rsc[row] * q_norm_w[k])
  gemm_bt_kernel<bf16, 2><<<dim3(NQX / 128, T / 128), 256, 0, stream>>>(
      cqkv, WqxT, qx, T, NQX, DC_Q, NDNP, rsc, q_norm_w);
  build_q_kernel<<<T, 256, 0, stream>>>(qx, pos_ids, cos_t, sin_t, Qp);
  attn_kernel<<<512, 512, 0, stream>>>(Qp, KcG, cTG, OC);
  gemm_bt_kernel<float, 0><<<dim3(D / 128, T / 128), 256, 0, stream>>>(
      OC, W2T, out, T, D, 256, 256, nullptr, nullptr);
}

// Round 14
// 154.801 us; speedup vs baseline: 1.0776x; 1.0776x over previous
//
#include <hip/hip_runtime.h>

typedef __bf16 bf16;
typedef __bf16 bf16x8 __attribute__((ext_vector_type(8)));
typedef __bf16 bf16x4 __attribute__((ext_vector_type(4)));
typedef float f32x4 __attribute__((ext_vector_type(4)));

constexpr int D = 2048, H = 16, DPH = 128, DR = 64, DC_KV = 16, DC_Q = 512;
constexpr int QHD = 192, MEG = 256, B = 2, S = 2048;
constexpr int T = B * S;
constexpr int NDNP = 640;   // fused down-proj width (512 q + 80 kv), padded to x128
constexpr int NQX = 1280;   // q gemm width: 256 absorbed qc + 1024 rope
constexpr float EPS = 1e-7f;
constexpr float KSC = 0.104124247f;  // (1/sqrt(192)) * log2(e), folded into Qp

static __device__ __forceinline__ bf16x8 zero8() {
  bf16x8 v;
#pragma unroll
  for (int j = 0; j < 8; j++) v[j] = (bf16)0.f;
  return v;
}

static __device__ __forceinline__ void gload_lds16(const bf16* g, bf16* l) {
  __builtin_amdgcn_global_load_lds(
      (const __attribute__((address_space(1))) unsigned int*)g,
      (__attribute__((address_space(3))) unsigned int*)l, 16, 0, 0);
}

#define LGWAIT0 do { asm volatile("s_waitcnt lgkmcnt(0)" ::: "memory"); __builtin_amdgcn_sched_barrier(0); } while (0)
#define VMWAIT0 do { asm volatile("s_waitcnt vmcnt(0)" ::: "memory"); __builtin_amdgcn_sched_barrier(0); } while (0)

// ---------------- rope table (f64 precision, once) ----------------
__global__ void rope_table_kernel(float* __restrict__ cos_t, float* __restrict__ sin_t) {
  int i = blockIdx.x * 64 + threadIdx.x;  // over S*32
  int pos = i >> 5, j = i & 31;
  double invf = pow(10000.0, -(double)(2 * j) / 64.0);
  double a = (double)pos * invf;
  cos_t[i] = (float)cos(a);
  sin_t[i] = (float)sin(a);
}

// ---------------- zero fill (bf16, n multiple of 8) ----------------
__global__ void zero_bf16_kernel(bf16* __restrict__ p, int n) {
  int i = (blockIdx.x * 256 + threadIdx.x) * 8;
  if (i < n) *reinterpret_cast<bf16x8*>(p + i) = zero8();
}

// ---------------- f32 -> bf16 cast ----------------
__global__ void cast_bf16_kernel(const float* __restrict__ in, bf16* __restrict__ out, int n) {
  int i = (blockIdx.x * blockDim.x + threadIdx.x) * 4;
  if (i < n) {
    float4 v = *reinterpret_cast<const float4*>(in + i);
    bf16x4 o;
    o[0] = (bf16)v.x; o[1] = (bf16)v.y; o[2] = (bf16)v.z; o[3] = (bf16)v.w;
    *reinterpret_cast<bf16x4*>(out + i) = o;
  }
}

// ---------------- transpose + cast: out[n][k] = (bf16) in[k][n], in is K x N f32 ----------------
__global__ __launch_bounds__(256) void transpose_cast_kernel(
    const float* __restrict__ in, bf16* __restrict__ out, int K, int N, int ldo) {
  __shared__ float tile[32][33];
  int k0 = blockIdx.y * 32, n0 = blockIdx.x * 32;
  int tid = threadIdx.x;
#pragma unroll
  for (int e = tid; e < 1024; e += 256) {
    int i = e >> 5, j = e & 31;
    int k = k0 + i, n = n0 + j;
    tile[i][j] = (k < K && n < N) ? in[(size_t)k * N + n] : 0.f;
  }
  __syncthreads();
#pragma unroll
  for (int e = tid; e < 1024; e += 256) {
    int jj = e >> 5, ii = e & 31;
    int n = n0 + jj, k = k0 + ii;
    if (k < K && n < N) out[(size_t)n * ldo + k] = (bf16)tile[ii][jj];
  }
}

// ---------------- W2T[d][h*16+c] = sum_v Wkv_up[c][h*256+128+v] * Wout[h*128+v][d] ----------------
__global__ __launch_bounds__(128) void prep_w2_kernel(
    const float* __restrict__ Wkv_up, const float* __restrict__ Wout,
    bf16* __restrict__ W2T) {
  __shared__ float wv[128][16];   // [v][c]
  int h = blockIdx.y, d0 = blockIdx.x * 128;
  int tid = threadIdx.x;
#pragma unroll
  for (int e = tid; e < 2048; e += 128) {
    int v = e >> 4, c = e & 15;
    wv[v][c] = Wkv_up[(size_t)c * (H * MEG) + h * MEG + 128 + v];
  }
  __syncthreads();
  int d = d0 + tid;
  float acc[16] = {};
  for (int v = 0; v < 128; v++) {
    float wo = Wout[(size_t)(h * 128 + v) * D + d];
    float4 a0 = *reinterpret_cast<const float4*>(&wv[v][0]);
    float4 a1 = *reinterpret_cast<const float4*>(&wv[v][4]);
    float4 a2 = *reinterpret_cast<const float4*>(&wv[v][8]);
    float4 a3 = *reinterpret_cast<const float4*>(&wv[v][12]);
    acc[0] += a0.x * wo;  acc[1] += a0.y * wo;  acc[2] += a0.z * wo;  acc[3] += a0.w * wo;
    acc[4] += a1.x * wo;  acc[5] += a1.y * wo;  acc[6] += a1.z * wo;  acc[7] += a1.w * wo;
    acc[8] += a2.x * wo;  acc[9] += a2.y * wo;  acc[10] += a2.z * wo; acc[11] += a2.w * wo;
    acc[12] += a3.x * wo; acc[13] += a3.y * wo; acc[14] += a3.z * wo; acc[15] += a3.w * wo;
  }
  bf16x8 o0, o1;
#pragma unroll
  for (int c = 0; c < 8; c++) { o0[c] = (bf16)acc[c]; o1[c] = (bf16)acc[8 + c]; }
  *reinterpret_cast<bf16x8*>(&W2T[(size_t)d * 256 + h * 16]) = o0;
  *reinterpret_cast<bf16x8*>(&W2T[(size_t)d * 256 + h * 16 + 8]) = o1;
}

// ---------------- WqxT[h*16+c][k] = sum_v Wq_up[k][h*192+v] * Wkv_up[c][h*256+v] ----------------
__global__ __launch_bounds__(128) void prep_w3_kernel(
    const float* __restrict__ Wq_up, const float* __restrict__ Wkv_up,
    bf16* __restrict__ WqxT) {
  __shared__ float wk[128][16];   // [v][c]
  int h = blockIdx.y, k0 = blockIdx.x * 128;
  int tid = threadIdx.x;
#pragma unroll
  for (int e = tid; e < 2048; e += 128) {
    int v = e >> 4, c = e & 15;
    wk[v][c] = Wkv_up[(size_t)c * (H * MEG) + h * MEG + v];
  }
  __syncthreads();
  int k = k0 + tid;
  float acc[16] = {};
  for (int v = 0; v < 128; v++) {
    float wq = Wq_up[(size_t)k * (H * QHD) + h * QHD + v];
    float4 a0 = *reinterpret_cast<const float4*>(&wk[v][0]);
    float4 a1 = *reinterpret_cast<const float4*>(&wk[v][4]);
    float4 a2 = *reinterpret_cast<const float4*>(&wk[v][8]);
    float4 a3 = *reinterpret_cast<const float4*>(&wk[v][12]);
    acc[0] += a0.x * wq;  acc[1] += a0.y * wq;  acc[2] += a0.z * wq;  acc[3] += a0.w * wq;
    acc[4] += a1.x * wq;  acc[5] += a1.y * wq;  acc[6] += a1.z * wq;  acc[7] += a1.w * wq;
    acc[8] += a2.x * wq;  acc[9] += a2.y * wq;  acc[10] += a2.z * wq; acc[11] += a2.w * wq;
    acc[12] += a3.x * wq; acc[13] += a3.y * wq; acc[14] += a3.z * wq; acc[15] += a3.w * wq;
  }
#pragma unroll
  for (int c = 0; c < 16; c++)
    WqxT[(size_t)(h * 16 + c) * DC_Q + k] = (bf16)acc[c];
}

// ---------------- WqxT[256 + h*64 + j][k] = Wq_up[k][h*192+128+j] (rope cols) ----------------
__global__ __launch_bounds__(256) void prep_wrope_kernel(
    const float* __restrict__ Wq_up, bf16* __restrict__ WqxT) {
  __shared__ float tile[64][65];
  int h = blockIdx.y, k0 = blockIdx.x * 64;
  int tid = threadIdx.x;
#pragma unroll
  for (int p = 0; p < 16; p++) {
    int kk = p * 4 + (tid >> 6), j = tid & 63;
    tile[kk][j] = Wq_up[(size_t)(k0 + kk) * (H * QHD) + h * QHD + 128 + j];
  }
  __syncthreads();
#pragma unroll
  for (int p = 0; p < 16; p++) {
    int n = p * 4 + (tid >> 6), k = tid & 63;
    WqxT[(size_t)(256 + h * 64 + n) * DC_Q + k0 + k] = (bf16)tile[k][n];
  }
}

// ---------------- RMSNorm over 512 dims (q path), input row stride ld ----------------
__global__ __launch_bounds__(256) void rmsnorm_q_kernel(
    const float* __restrict__ cq, const float* __restrict__ w, bf16* __restrict__ outp, int ld) {
  int wid = threadIdx.x >> 6, lane = threadIdx.x & 63;
  int t = blockIdx.x * 4 + wid;
  const float* x = cq + (size_t)t * ld;
  float4 v0 = *reinterpret_cast<const float4*>(x + lane * 8);
  float4 v1 = *reinterpret_cast<const float4*>(x + lane * 8 + 4);
  float ss = v0.x * v0.x + v0.y * v0.y + v0.z * v0.z + v0.w * v0.w +
             v1.x * v1.x + v1.y * v1.y + v1.z * v1.z + v1.w * v1.w;
#pragma unroll
  for (int off = 32; off; off >>= 1) ss += __shfl_xor(ss, off);
  float r = rsqrtf(ss / (float)DC_Q + EPS);
  const float* wp = w + lane * 8;
  float vv[8] = {v0.x, v0.y, v0.z, v0.w, v1.x, v1.y, v1.z, v1.w};
  bf16x8 o;
#pragma unroll
  for (int j = 0; j < 8; j++) o[j] = (bf16)(vv[j] * r * wp[j]);
  *reinterpret_cast<bf16x8*>(outp + (size_t)t * DC_Q + lane * 8) = o;
}

// ---------------- kv prep: Kc row = [rope64 | c16 | zero pad..128]; cT[c][s] = c_kv^T ----------------
__global__ __launch_bounds__(64) void kv_prep_kernel(
    const float* __restrict__ cqkv, const float* __restrict__ kvw,
    const int* __restrict__ pos_ids,
    const float* __restrict__ cos_t, const float* __restrict__ sin_t,
    bf16* __restrict__ KcG, bf16* __restrict__ cTG) {
  int t = blockIdx.x;
  int lane = threadIdx.x;
  int b = t >> 11, s = t & (S - 1);
  const float* x = cqkv + (size_t)t * NDNP + DC_Q;
  float v = (lane < 16) ? x[lane] : 0.f;
  float ss = v * v;
#pragma unroll
  for (int off = 1; off < 16; off <<= 1) ss += __shfl_xor(ss, off);
  float r = rsqrtf(ss / 16.f + EPS);
  bf16* krow = KcG + ((size_t)t << 7);
  if (lane < 16) {
    bf16 cn = (bf16)(v * r * kvw[lane]);
    krow[64 + lane] = cn;
    cTG[(size_t)(b * 16 + lane) * S + s] = cn;
  } else {
    krow[64 + lane] = (bf16)0.f;   // dims 80..127 zero
  }
  if (lane < 32) {
    int j = lane;
    int pos = pos_ids[t];
    float cf = cos_t[pos * 32 + j], sf = sin_t[pos * 32 + j];
    float x0 = x[16 + 2 * j], x1 = x[16 + 2 * j + 1];
    krow[j]      = (bf16)(x0 * cf - x1 * sf);
    krow[32 + j] = (bf16)(x1 * cf + x0 * sf);
  }
}

// ---------------- build Qp (B*H, S, 96) = KSC*[rope64 | qc16 | zero16] from qx ----------------
__global__ __launch_bounds__(256) void build_q_kernel(
    const bf16* __restrict__ qx, const int* __restrict__ pos_ids,
    const float* __restrict__ cos_t, const float* __restrict__ sin_t,
    bf16* __restrict__ Qp) {
  int t = blockIdx.x;
  int b = t >> 11, s = t & (S - 1);
  int tid = threadIdx.x;
  int pos = pos_ids[t];
  const bf16* qr = qx + (size_t)t * NQX;
#pragma unroll
  for (int rep = 0; rep < 2; rep++) {
    int item = rep * 256 + tid;
    int h = item >> 5, j = item & 31;
    float cf = cos_t[pos * 32 + j], sf = sin_t[pos * 32 + j];
    float x0 = (float)qr[256 + h * 64 + 2 * j], x1 = (float)qr[256 + h * 64 + 2 * j + 1];
    bf16* qrow = Qp + (size_t)((b * 16 + h) * 2048 + s) * 96;
    qrow[j]      = (bf16)((x0 * cf - x1 * sf) * KSC);
    qrow[32 + j] = (bf16)((x1 * cf + x0 * sf) * KSC);
  }
  {
    int h = tid >> 4, c = tid & 15;
    bf16* qrow = Qp + (size_t)((b * 16 + h) * 2048 + s) * 96;
    qrow[64 + c] = (bf16)((float)qr[h * 16 + c] * KSC);
    qrow[80 + c] = (bf16)0.f;
  }
}

// ---------------- bf16 MFMA GEMM, 64x128 tile, dbuf + counted vmcnt ----------------
// C(MxN) = A(MxK) * Bt(NxK)^T. 256 threads = 4 waves; wave w owns 64M x 32N (acc 4x2).
// Small tile -> large grids (2-4 blocks/CU) -> cross-block latency overlap; LDS 48KB.
template <typename OutT>
__global__ __launch_bounds__(256) void gemm_bt_kernel(
    const bf16* __restrict__ A, const bf16* __restrict__ Bt,
    OutT* __restrict__ C, int M, int N, int K) {
  __shared__ bf16 As[2][64 * 64];
  __shared__ bf16 Bs[2][128 * 64];
  int tid = threadIdx.x;
  int wid = tid >> 6, lane = tid & 63;
  int g = lane >> 4, c = lane & 15;
  int nbx = gridDim.x;                 // N / 128
  int lin = blockIdx.y * nbx + blockIdx.x;
  int cpx = (nbx * gridDim.y) >> 3;    // grid % 8 == 0 for all uses
  int swz = (lin & 7) * cpx + (lin >> 3);
  int m0 = (swz / nbx) * 64, n0 = (swz % nbx) * 128;
  int lrow8 = tid >> 3, lslot = tid & 7;   // 32 rows x 8 slots per round

  auto stage = [&](int kt, int buf) {
    int k0 = kt << 6;
#pragma unroll
    for (int r = 0; r < 2; r++) {
      int row = r * 32 + lrow8;
      int sslot = lslot ^ (row & 7);
      gload_lds16(A + (size_t)(m0 + row) * K + k0 + sslot * 8, &As[buf][row * 64 + lslot * 8]);
    }
#pragma unroll
    for (int r = 0; r < 4; r++) {
      int row = r * 32 + lrow8;
      int sslot = lslot ^ (row & 7);
      gload_lds16(Bt + (size_t)(n0 + row) * K + k0 + sslot * 8, &Bs[buf][row * 64 + lslot * 8]);
    }
  };

  f32x4 acc[4][2] = {};
  int nk = K >> 6;
  stage(0, 0);
  __builtin_amdgcn_sched_barrier(0);
  for (int kt = 0; kt < nk; kt++) {
    int cur = kt & 1;
    __builtin_amdgcn_s_barrier();     // A: buf[cur^1] readers done
    __builtin_amdgcn_sched_barrier(0);
    if (kt + 1 < nk) {
      stage(kt + 1, cur ^ 1);
      asm volatile("s_waitcnt vmcnt(6)" ::: "memory");   // tile kt's 6 loads landed
    } else {
      asm volatile("s_waitcnt vmcnt(0)" ::: "memory");
    }
    __builtin_amdgcn_sched_barrier(0);
    __builtin_amdgcn_s_barrier();     // B: buf[cur] fully staged
    __builtin_amdgcn_sched_barrier(0);
#pragma unroll
    for (int kk = 0; kk < 2; kk++) {
      bf16x8 af[4], bfr[2];
#pragma unroll
      for (int mi = 0; mi < 4; mi++) {
        int row = mi * 16 + c;
        int sl = (kk * 4 + g) ^ (row & 7);
        af[mi] = *reinterpret_cast<const bf16x8*>(&As[cur][row * 64 + sl * 8]);
      }
#pragma unroll
      for (int ni = 0; ni < 2; ni++) {
        int row = wid * 32 + ni * 16 + c;
        int sl = (kk * 4 + g) ^ (row & 7);
        bfr[ni] = *reinterpret_cast<const bf16x8*>(&Bs[cur][row * 64 + sl * 8]);
      }
#pragma unroll
      for (int mi = 0; mi < 4; mi++)
#pragma unroll
        for (int ni = 0; ni < 2; ni++)
          acc[mi][ni] = __builtin_amdgcn_mfma_f32_16x16x32_bf16(af[mi], bfr[ni], acc[mi][ni], 0, 0, 0);
    }
  }
#pragma unroll
  for (int mi = 0; mi < 4; mi++)
#pragma unroll
    for (int ni = 0; ni < 2; ni++)
#pragma unroll
      for (int r = 0; r < 4; r++) {
        int row = m0 + mi * 16 + g * 4 + r;
        int col = n0 + wid * 32 + ni * 16 + c;
        C[(size_t)row * N + col] = (OutT)acc[mi][ni][r];
      }
}

// ---------------- absorbed flash attention, single-Kls reg-staged, 2 blocks/CU ----------------
__global__ __launch_bounds__(512, 4) void attn_kernel(
    const bf16* __restrict__ Qp, const bf16* __restrict__ KcG,
    const bf16* __restrict__ cTG, bf16* __restrict__ OC) {
  __shared__ bf16 Kls[128 * 128];     // 32KB: entry (key,e): e holds slot e^(key>>3)
  __shared__ bf16 Cls[2][16 * 128];   // 4KB x2: entry (c,e): e holds slot e^c
  __shared__ bf16 Pls[8][16 * 128];   // 4KB per wave

  int lin = blockIdx.x;               // 0..511
  int v = lin >> 8, u = lin & 255;
  int qt = v ? (u >> 1) : (127 - (u >> 1));   // anti-correlated heavy/light halves
  int hg = u & 1, b = v;
  int q0 = qt * 16;
  int nt = qt / 8 + 1;
  int tid = threadIdx.x;
  int w = tid >> 6, lane = tid & 63;
  int g = lane >> 4, cc = lane & 15;
  int h = hg * 8 + w;
  char* pbase = reinterpret_cast<char*>(&Pls[w][0]);

  bf16x8 kst[4];
  auto load_k = [&](int k0) {
#pragma unroll
    for (int i = 0; i < 4; i++) {
      int id = w * 4 + i;
      int key = id * 4 + (lane >> 4);
      int sg = (lane & 15) ^ ((id >> 1) & 15);
      kst[i] = *reinterpret_cast<const bf16x8*>(
          KcG + (((size_t)(b * S + k0 + key)) << 7) + sg * 8);
    }
  };
  auto write_k = [&]() {
#pragma unroll
    for (int i = 0; i < 4; i++) {
      int id = w * 4 + i;
      *reinterpret_cast<bf16x8*>(&Kls[(id * 64 + lane) * 8]) = kst[i];
    }
  };
  auto stage_c = [&](int k0, int buf) {
    if (w >= 4) {
      int c = (w - 4) * 4 + (lane >> 4);
      int sg = (lane & 15) ^ c;
      gload_lds16(cTG + (size_t)(b * 16 + c) * S + k0 + sg * 8,
                  &Cls[buf][(w - 4) * 512]);
    }
  };

  // ---- Q fragments (pre-scaled by KSC at build time) ----
  bf16x8 aq[3];
  const bf16* qp = Qp + (size_t)((b * 16 + h) * 2048 + q0 + cc) * 96;
#pragma unroll
  for (int kk = 0; kk < 3; kk++)
    aq[kk] = *reinterpret_cast<const bf16x8*>(qp + kk * 32 + g * 8);

  // ---- prologue ----
  stage_c(0, 0);
  __builtin_amdgcn_sched_barrier(0);
  load_k(0);
  VMWAIT0;                        // K0 regs + C0 landed
  write_k();
  if (nt > 1) {
    stage_c(128, 1);
    __builtin_amdgcn_sched_barrier(0);
    load_k(128);
  }
  LGWAIT0;
  __builtin_amdgcn_s_barrier();   // Kls tile0 + Cls[0] ready
  __builtin_amdgcn_sched_barrier(0);

  bf16x8 ones;
#pragma unroll
  for (int j = 0; j < 8; j++) ones[j] = (bf16)1.f;

  f32x4 oc = {}, ls = {};

#pragma unroll 1
  for (int kt = 0; kt < nt; kt++) {
    int cur = kt & 1;
    int k0 = kt * 128;
    // ---- QK^T over 96 dims (3 K-steps) x 128 keys; col cc of MFMA ntb = key cc*8+ntb ----
    f32x4 sacc[8] = {};
    __builtin_amdgcn_s_setprio(1);
#pragma unroll
    for (int kk = 0; kk < 3; kk++)
#pragma unroll
      for (int ntb = 0; ntb < 8; ntb++) {
        int key = cc * 8 + ntb;
        bf16x8 bk = *reinterpret_cast<const bf16x8*>(
            &Kls[(key * 16 + ((kk * 4 + g) ^ cc)) * 8]);
        sacc[ntb] = __builtin_amdgcn_mfma_f32_16x16x32_bf16(aq[kk], bk, sacc[ntb], 0, 0, 0);
      }
    __builtin_amdgcn_s_setprio(0);

    // ---- max-free softmax: p = exp2(s') (s' pre-scaled); masked -> exp2(-1e30) = 0 ----
    bool diag = (kt == nt - 1);
#pragma unroll
    for (int r = 0; r < 4; r++) {
      bf16x8 pk;
#pragma unroll
      for (int ntb = 0; ntb < 8; ntb++) {
        float x = sacc[ntb][r];
        if (diag) {
          int qr = q0 + g * 4 + r, kc = k0 + cc * 8 + ntb;
          if (kc > qr) x = -1e30f;
        }
        pk[ntb] = (bf16)__builtin_amdgcn_exp2f(x);
      }
      int q = g * 4 + r;
      *reinterpret_cast<bf16x8*>(pbase + (q * 16 + (cc ^ (q & 7))) * 16) = pk;
    }
    LGWAIT0;
    // ---- PV + row-sum via ones-MFMA (matrix pipe does the reduction) ----
    __builtin_amdgcn_s_setprio(1);
#pragma unroll
    for (int kk2 = 0; kk2 < 4; kk2++) {
      bf16x8 pa = *reinterpret_cast<const bf16x8*>(
          pbase + (cc * 16 + ((kk2 * 4 + g) ^ (cc & 7))) * 16);
      bf16x8 bv = *reinterpret_cast<const bf16x8*>(
          &Cls[cur][(cc * 16 + ((kk2 * 4 + g) ^ cc)) * 8]);
      oc = __builtin_amdgcn_mfma_f32_16x16x32_bf16(pa, bv, oc, 0, 0, 0);
      ls = __builtin_amdgcn_mfma_f32_16x16x32_bf16(pa, ones, ls, 0, 0, 0);
    }
    __builtin_amdgcn_s_setprio(0);

    if (kt + 1 < nt) {
      __builtin_amdgcn_s_barrier();     // A: all waves done reading Kls & Cls[cur]
      __builtin_amdgcn_sched_barrier(0);
      VMWAIT0;                          // K(kt+1) regs + C(kt+1) landed (issued 1 tile ago)
      write_k();                        // K(kt+1) -> Kls
      if (kt + 2 < nt) {
        stage_c((kt + 2) * 128, cur);   // C(kt+2) -> Cls[cur] (free after barrier A)
        __builtin_amdgcn_sched_barrier(0);
        load_k((kt + 2) * 128);
      }
      LGWAIT0;                          // my ds_writes drained
      __builtin_amdgcn_s_barrier();     // B: Kls tile kt+1 visible
      __builtin_amdgcn_sched_barrier(0);
    }
  }

  // ---- epilogue ----
#pragma unroll
  for (int r = 0; r < 4; r++) {
    size_t t = (size_t)b * S + q0 + g * 4 + r;
    OC[t * 256 + h * 16 + cc] = (bf16)(oc[r] / ls[r]);
  }
}

// ---------------- host ----------------
extern "C" void kernel_launch(void* const* d_in, const int* in_sizes, int n_in,
                              void* d_out, int out_size, void* d_ws, size_t ws_size,
                              hipStream_t stream) {
  const float* inputs    = (const float*)d_in[0];
  const int*   pos_ids   = (const int*)d_in[1];
  const float* Wq_down   = (const float*)d_in[3];
  const float* q_norm_w  = (const float*)d_in[4];
  const float* Wq_up     = (const float*)d_in[5];
  const float* Wkv_down  = (const float*)d_in[6];
  const float* kv_norm_w = (const float*)d_in[7];
  const float* Wkv_up    = (const float*)d_in[8];
  const float* Wout      = (const float*)d_in[9];
  float* out = (float*)d_out;

  char* ws = (char*)d_ws;
  size_t off = 0;
  auto alloc = [&](size_t bytes) -> void* {
    void* p = ws + off;
    off += (bytes + 255) & ~(size_t)255;
    return p;
  };

  bf16*  in_bf = (bf16*)alloc((size_t)T * D * 2);
  bf16*  WdT   = (bf16*)alloc((size_t)NDNP * D * 2);        // fused down-proj weights^T
  bf16*  WqxT  = (bf16*)alloc((size_t)NQX * DC_Q * 2);      // [absorbed qc 256 | rope 1024] x 512
  bf16*  W2T   = (bf16*)alloc((size_t)D * 256 * 2);         // absorbed out-proj weights^T
  float* cqkv  = (float*)alloc((size_t)T * NDNP * 4);
  bf16*  cqn   = (bf16*)alloc((size_t)T * DC_Q * 2);
  bf16*  qx    = (bf16*)alloc((size_t)T * NQX * 2);         // q gemm output
  bf16*  KcG   = (bf16*)alloc((size_t)T * 128 * 2);         // [rope64|c16|pad] per token
  bf16*  cTG   = (bf16*)alloc((size_t)B * 16 * S * 2);      // c_kv^T per batch
  bf16*  Qp    = (bf16*)alloc((size_t)B * H * S * 96 * 2);  // absorbed Q (pre-scaled)
  bf16*  OC    = (bf16*)alloc((size_t)T * H * 16 * 2);      // attention out in c-space
  float* cos_t = (float*)alloc((size_t)S * 32 * 4);
  float* sin_t = (float*)alloc((size_t)S * 32 * 4);

  rope_table_kernel<<<S * 32 / 64, 64, 0, stream>>>(cos_t, sin_t);
  cast_bf16_kernel<<<(T * D / 4 + 255) / 256, 256, 0, stream>>>(inputs, in_bf, T * D);
  zero_bf16_kernel<<<(NDNP * D / 8 + 255) / 256, 256, 0, stream>>>(WdT, NDNP * D);
  transpose_cast_kernel<<<dim3((DC_Q + 31) / 32, (D + 31) / 32), 256, 0, stream>>>(Wq_down, WdT, D, DC_Q, D);
  transpose_cast_kernel<<<dim3((80 + 31) / 32, (D + 31) / 32), 256, 0, stream>>>(Wkv_down, WdT + (size_t)DC_Q * D, D, 80, D);
  prep_w3_kernel<<<dim3(4, 16), 128, 0, stream>>>(Wq_up, Wkv_up, WqxT);
  prep_wrope_kernel<<<dim3(8, 16), 256, 0, stream>>>(Wq_up, WqxT);
  prep_w2_kernel<<<dim3(16, 16), 128, 0, stream>>>(Wkv_up, Wout, W2T);

  gemm_bt_kernel<float><<<dim3(NDNP / 128, T / 64), 256, 0, stream>>>(in_bf, WdT, cqkv, T, NDNP, D);
  rmsnorm_q_kernel<<<T / 4, 256, 0, stream>>>(cqkv, q_norm_w, cqn, NDNP);
  kv_prep_kernel<<<T, 64, 0, stream>>>(cqkv, kv_norm_w, pos_ids, cos_t, sin_t, KcG, cTG);
  gemm_bt_kernel<bf16><<<dim3(NQX / 128, T / 64), 256, 0, stream>>>(cqn, WqxT, qx, T, NQX, DC_Q);
  build_q_kernel<<<T, 256, 0, stream>>>(qx, pos_ids, cos_t, sin_t, Qp);
  attn_kernel<<<512, 512, 0, stream>>>(Qp, KcG, cTG, OC);
  gemm_bt_kernel<float><<<dim3(D / 128, T / 64), 256, 0, stream>>>(OC, W2T, out, T, D, 256);
}

// Round 16
// 136.481 us; speedup vs baseline: 1.2222x; 1.1342x over previous
//
#include <hip/hip_runtime.h>

typedef __bf16 bf16;
typedef __bf16 bf16x8 __attribute__((ext_vector_type(8)));
typedef __bf16 bf16x4 __attribute__((ext_vector_type(4)));
typedef float f32x4 __attribute__((ext_vector_type(4)));

constexpr int D = 2048, H = 16, DPH = 128, DR = 64, DC_KV = 16, DC_Q = 512;
constexpr int QHD = 192, MEG = 256, B = 2, S = 2048;
constexpr int T = B * S;
constexpr int NDNP = 640;   // fused down-proj width (512 q + 80 kv), padded to x128
constexpr int NQX = 1280;   // q gemm width: 256 absorbed qc + 1024 rope
constexpr float EPS = 1e-7f;
constexpr float KSC = 0.104124247f;  // (1/sqrt(192)) * log2(e), folded into Qp

static __device__ __forceinline__ bf16x8 zero8() {
  bf16x8 v;
#pragma unroll
  for (int j = 0; j < 8; j++) v[j] = (bf16)0.f;
  return v;
}

static __device__ __forceinline__ void gload_lds16(const bf16* g, bf16* l) {
  __builtin_amdgcn_global_load_lds(
      (const __attribute__((address_space(1))) unsigned int*)g,
      (__attribute__((address_space(3))) unsigned int*)l, 16, 0, 0);
}

#define LGWAIT0 do { asm volatile("s_waitcnt lgkmcnt(0)" ::: "memory"); __builtin_amdgcn_sched_barrier(0); } while (0)
#define VMWAIT0 do { asm volatile("s_waitcnt vmcnt(0)" ::: "memory"); __builtin_amdgcn_sched_barrier(0); } while (0)

// ================= mega prologue: all input-independent prep in ONE launch =================
// All write regions are pairwise DISJOINT (no inter-block ordering needed):
// blocks [0,8192)      : cast inputs f32 -> in_bf
// blocks [8192,8240)   : zero WdT pad rows [592,640)  (transposes never touch these)
// blocks [8240,9264)   : transpose Wq_down -> WdT rows [0,512)
// blocks [9264,9456)   : transpose Wkv_down -> WdT rows [512,592)
// blocks [9456,9520)   : prep_w3 -> WqxT rows [0,256)
// blocks [9520,9648)   : prep_wrope -> WqxT rows [256,1280)
// blocks [9648,9904)   : prep_w2 -> W2T
// blocks [9904,10160)  : rope table
__global__ __launch_bounds__(256) void prologue_kernel(
    const float* __restrict__ inputs, const float* __restrict__ Wq_down,
    const float* __restrict__ Wq_up, const float* __restrict__ Wkv_down,
    const float* __restrict__ Wkv_up, const float* __restrict__ Wout,
    bf16* __restrict__ in_bf, bf16* __restrict__ WdT, bf16* __restrict__ WqxT,
    bf16* __restrict__ W2T, float* __restrict__ cos_t, float* __restrict__ sin_t) {
  __shared__ float smem[64 * 65];
  int bid = blockIdx.x;
  int tid = threadIdx.x;

  if (bid < 8192) {                       // ---- cast ----
    int i = (bid * 256 + tid) * 4;
    float4 v = *reinterpret_cast<const float4*>(inputs + i);
    bf16x4 o;
    o[0] = (bf16)v.x; o[1] = (bf16)v.y; o[2] = (bf16)v.z; o[3] = (bf16)v.w;
    *reinterpret_cast<bf16x4*>(in_bf + i) = o;
  } else if (bid < 8240) {                // ---- zero WdT pad rows only ----
    size_t i = (size_t)592 * D + ((size_t)(bid - 8192) * 256 + tid) * 8;
    *reinterpret_cast<bf16x8*>(WdT + i) = zero8();
  } else if (bid < 9456) {                // ---- transposes ----
    const float* src; bf16* dst; int K, N, k0, n0;
    if (bid < 9264) {
      int lb = bid - 8240;
      src = Wq_down; dst = WdT; K = D; N = DC_Q;
      k0 = (lb >> 4) * 32; n0 = (lb & 15) * 32;
    } else {
      int lb = bid - 9264;
      src = Wkv_down; dst = WdT + (size_t)DC_Q * D; K = D; N = 80;
      k0 = (lb / 3) * 32; n0 = (lb % 3) * 32;
    }
    float (*tile)[33] = (float(*)[33])smem;
#pragma unroll
    for (int e = tid; e < 1024; e += 256) {
      int i = e >> 5, j = e & 31;
      int k = k0 + i, n = n0 + j;
      tile[i][j] = (k < K && n < N) ? src[(size_t)k * N + n] : 0.f;
    }
    __syncthreads();
#pragma unroll
    for (int e = tid; e < 1024; e += 256) {
      int jj = e >> 5, ii = e & 31;
      int n = n0 + jj, k = k0 + ii;
      if (k < K && n < N) dst[(size_t)n * D + k] = (bf16)tile[ii][jj];
    }
  } else if (bid < 9520) {                // ---- prep_w3 ----
    int lb = bid - 9456;
    int h = lb >> 2, k0 = (lb & 3) * 128;
    float (*wk)[16] = (float(*)[16])smem;
#pragma unroll
    for (int e = tid; e < 2048; e += 256) {
      int v = e >> 4, c = e & 15;
      wk[v][c] = Wkv_up[(size_t)c * (H * MEG) + h * MEG + v];
    }
    __syncthreads();
    if (tid < 128) {
      int k = k0 + tid;
      float acc[16] = {};
      for (int v = 0; v < 128; v++) {
        float wq = Wq_up[(size_t)k * (H * QHD) + h * QHD + v];
#pragma unroll
        for (int c = 0; c < 16; c++) acc[c] += wk[v][c] * wq;
      }
#pragma unroll
      for (int c = 0; c < 16; c++)
        WqxT[(size_t)(h * 16 + c) * DC_Q + k] = (bf16)acc[c];
    }
  } else if (bid < 9648) {                // ---- prep_wrope ----
    int lb = bid - 9520;
    int h = lb >> 3, k0 = (lb & 7) * 64;
    float (*tile)[65] = (float(*)[65])smem;
#pragma unroll
    for (int p = 0; p < 16; p++) {
      int kk = p * 4 + (tid >> 6), j = tid & 63;
      tile[kk][j] = Wq_up[(size_t)(k0 + kk) * (H * QHD) + h * QHD + 128 + j];
    }
    __syncthreads();
#pragma unroll
    for (int p = 0; p < 16; p++) {
      int n = p * 4 + (tid >> 6), k = tid & 63;
      WqxT[(size_t)(256 + h * 64 + n) * DC_Q + k0 + k] = (bf16)tile[k][n];
    }
  } else if (bid < 9904) {                // ---- prep_w2 ----
    int lb = bid - 9648;
    int h = lb >> 4, d0 = (lb & 15) * 128;
    float (*wv)[16] = (float(*)[16])smem;
#pragma unroll
    for (int e = tid; e < 2048; e += 256) {
      int v = e >> 4, c = e & 15;
      wv[v][c] = Wkv_up[(size_t)c * (H * MEG) + h * MEG + 128 + v];
    }
    __syncthreads();
    if (tid < 128) {
      int d = d0 + tid;
      float acc[16] = {};
      for (int v = 0; v < 128; v++) {
        float wo = Wout[(size_t)(h * 128 + v) * D + d];
#pragma unroll
        for (int c = 0; c < 16; c++) acc[c] += wv[v][c] * wo;
      }
      bf16x8 o0, o1;
#pragma unroll
      for (int c = 0; c < 8; c++) { o0[c] = (bf16)acc[c]; o1[c] = (bf16)acc[8 + c]; }
      *reinterpret_cast<bf16x8*>(&W2T[(size_t)d * 256 + h * 16]) = o0;
      *reinterpret_cast<bf16x8*>(&W2T[(size_t)d * 256 + h * 16 + 8]) = o1;
    }
  } else {                                // ---- rope table ----
    int i = (bid - 9904) * 256 + tid;     // over S*32
    int pos = i >> 5, j = i & 31;
    double invf = pow(10000.0, -(double)(2 * j) / 64.0);
    double a = (double)pos * invf;
    cos_t[i] = (float)cos(a);
    sin_t[i] = (float)sin(a);
  }
}

// ======== merged rmsnorm(q) + kv prep: 1 wave per token ========
__global__ __launch_bounds__(256) void norm_kv_kernel(
    const float* __restrict__ cqkv, const float* __restrict__ qw,
    const float* __restrict__ kvw, const int* __restrict__ pos_ids,
    const float* __restrict__ cos_t, const float* __restrict__ sin_t,
    bf16* __restrict__ cqn, bf16* __restrict__ KcG, bf16* __restrict__ cTG) {
  int w = threadIdx.x >> 6, lane = threadIdx.x & 63;
  int t = blockIdx.x * 4 + w;
  int b = t >> 11, s = t & (S - 1);
  const float* x = cqkv + (size_t)t * NDNP;
  // ---- q rmsnorm over [0,512) ----
  float4 v0 = *reinterpret_cast<const float4*>(x + lane * 8);
  float4 v1 = *reinterpret_cast<const float4*>(x + lane * 8 + 4);
  float ss = v0.x * v0.x + v0.y * v0.y + v0.z * v0.z + v0.w * v0.w +
             v1.x * v1.x + v1.y * v1.y + v1.z * v1.z + v1.w * v1.w;
#pragma unroll
  for (int off = 32; off; off >>= 1) ss += __shfl_xor(ss, off);
  float r = rsqrtf(ss / (float)DC_Q + EPS);
  const float* wp = qw + lane * 8;
  float vv[8] = {v0.x, v0.y, v0.z, v0.w, v1.x, v1.y, v1.z, v1.w};
  bf16x8 o;
#pragma unroll
  for (int j = 0; j < 8; j++) o[j] = (bf16)(vv[j] * r * wp[j]);
  *reinterpret_cast<bf16x8*>(cqn + (size_t)t * DC_Q + lane * 8) = o;
  // ---- kv prep over [512,592) ----
  const float* xk = x + DC_Q;
  float vk = (lane < 16) ? xk[lane] : 0.f;
  float sk = vk * vk;
#pragma unroll
  for (int off = 1; off < 16; off <<= 1) sk += __shfl_xor(sk, off);
  float rk = rsqrtf(sk / 16.f + EPS);
  bf16* krow = KcG + ((size_t)t << 7);
  if (lane < 16) {
    bf16 cn = (bf16)(vk * rk * kvw[lane]);
    krow[64 + lane] = cn;
    cTG[(size_t)(b * 16 + lane) * S + s] = cn;
  } else {
    krow[64 + lane] = (bf16)0.f;   // dims 80..127 zero
  }
  if (lane < 32) {
    int j = lane;
    int pos = pos_ids[t];
    float cf = cos_t[pos * 32 + j], sf = sin_t[pos * 32 + j];
    float x0 = xk[16 + 2 * j], x1 = xk[16 + 2 * j + 1];
    krow[j]      = (bf16)(x0 * cf - x1 * sf);
    krow[32 + j] = (bf16)(x1 * cf + x0 * sf);
  }
}

// ---------------- bf16 MFMA GEMM, 64x128 tile, dbuf + counted vmcnt ----------------
// EPI 0: plain C write. EPI 1: q-path epilogue -> writes Qp (RoPE via lane-pair shfl,
// KSC fold); qc tiles (n0<256) write Qp[64+c] and zero [80+c].
template <typename OutT, int EPI>
__global__ __launch_bounds__(256) void gemm_bt_kernel(
    const bf16* __restrict__ A, const bf16* __restrict__ Bt,
    OutT* __restrict__ C, int M, int N, int K,
    const int* __restrict__ pos_ids = nullptr,
    const float* __restrict__ cos_t = nullptr,
    const float* __restrict__ sin_t = nullptr,
    bf16* __restrict__ Qp = nullptr) {
  __shared__ bf16 As[2][64 * 64];
  __shared__ bf16 Bs[2][128 * 64];
  int tid = threadIdx.x;
  int wid = tid >> 6, lane = tid & 63;
  int g = lane >> 4, c = lane & 15;
  int nbx = gridDim.x;                 // N / 128
  int lin = blockIdx.y * nbx + blockIdx.x;
  int cpx = (nbx * gridDim.y) >> 3;    // grid % 8 == 0 for all uses
  int swz = (lin & 7) * cpx + (lin >> 3);
  int m0 = (swz / nbx) * 64, n0 = (swz % nbx) * 128;
  int lrow8 = tid >> 3, lslot = tid & 7;

  auto stage = [&](int kt, int buf) {
    int k0 = kt << 6;
#pragma unroll
    for (int r = 0; r < 2; r++) {
      int row = r * 32 + lrow8;
      int sslot = lslot ^ (row & 7);
      gload_lds16(A + (size_t)(m0 + row) * K + k0 + sslot * 8, &As[buf][row * 64 + lslot * 8]);
    }
#pragma unroll
    for (int r = 0; r < 4; r++) {
      int row = r * 32 + lrow8;
      int sslot = lslot ^ (row & 7);
      gload_lds16(Bt + (size_t)(n0 + row) * K + k0 + sslot * 8, &Bs[buf][row * 64 + lslot * 8]);
    }
  };

  f32x4 acc[4][2] = {};
  int nk = K >> 6;
  stage(0, 0);
  __builtin_amdgcn_sched_barrier(0);
  for (int kt = 0; kt < nk; kt++) {
    int cur = kt & 1;
    __builtin_amdgcn_s_barrier();
    __builtin_amdgcn_sched_barrier(0);
    if (kt + 1 < nk) {
      stage(kt + 1, cur ^ 1);
      asm volatile("s_waitcnt vmcnt(6)" ::: "memory");
    } else {
      asm volatile("s_waitcnt vmcnt(0)" ::: "memory");
    }
    __builtin_amdgcn_sched_barrier(0);
    __builtin_amdgcn_s_barrier();
    __builtin_amdgcn_sched_barrier(0);
#pragma unroll
    for (int kk = 0; kk < 2; kk++) {
      bf16x8 af[4], bfr[2];
#pragma unroll
      for (int mi = 0; mi < 4; mi++) {
        int row = mi * 16 + c;
        int sl = (kk * 4 + g) ^ (row & 7);
        af[mi] = *reinterpret_cast<const bf16x8*>(&As[cur][row * 64 + sl * 8]);
      }
#pragma unroll
      for (int ni = 0; ni < 2; ni++) {
        int row = wid * 32 + ni * 16 + c;
        int sl = (kk * 4 + g) ^ (row & 7);
        bfr[ni] = *reinterpret_cast<const bf16x8*>(&Bs[cur][row * 64 + sl * 8]);
      }
#pragma unroll
      for (int mi = 0; mi < 4; mi++)
#pragma unroll
        for (int ni = 0; ni < 2; ni++)
          acc[mi][ni] = __builtin_amdgcn_mfma_f32_16x16x32_bf16(af[mi], bfr[ni], acc[mi][ni], 0, 0, 0);
    }
  }

  if constexpr (EPI == 0) {
#pragma unroll
    for (int mi = 0; mi < 4; mi++)
#pragma unroll
      for (int ni = 0; ni < 2; ni++)
#pragma unroll
        for (int r = 0; r < 4; r++) {
          int row = m0 + mi * 16 + g * 4 + r;
          int col = n0 + wid * 32 + ni * 16 + c;
          C[(size_t)row * N + col] = (OutT)acc[mi][ni][r];
        }
  } else {
    // q-path epilogue: write absorbed Q directly
    bool ropeTile = (n0 >= 256);
#pragma unroll
    for (int mi = 0; mi < 4; mi++)
#pragma unroll
      for (int r = 0; r < 4; r++) {
        int row = m0 + mi * 16 + g * 4 + r;       // token t
        int b = row >> 11, s = row & (S - 1);
#pragma unroll
        for (int ni = 0; ni < 2; ni++) {
          int col = n0 + wid * 32 + ni * 16 + c;
          float val = acc[mi][ni][r];
          if (!ropeTile) {
            int h = col >> 4, cq = col & 15;
            bf16* qrow = Qp + (size_t)((b * 16 + h) * 2048 + s) * 96;
            qrow[64 + cq] = (bf16)(val * KSC);
            qrow[80 + cq] = (bf16)0.f;
          } else {
            int colr = col - 256;
            int h = colr >> 6, jj = colr & 63, j = jj >> 1;
            int pos = pos_ids[row];
            float cf = cos_t[pos * 32 + j], sf = sin_t[pos * 32 + j];
            float other = __shfl_xor(val, 1);
            bf16* qrow = Qp + (size_t)((b * 16 + h) * 2048 + s) * 96;
            if ((c & 1) == 0) {
              qrow[j] = (bf16)((val * cf - other * sf) * KSC);
            } else {
              qrow[32 + j] = (bf16)((val * cf + other * sf) * KSC);
            }
          }
        }
      }
  }
}

// ---------------- absorbed flash attention, single-Kls reg-staged, 2 blocks/CU ----------------
__global__ __launch_bounds__(512, 4) void attn_kernel(
    const bf16* __restrict__ Qp, const bf16* __restrict__ KcG,
    const bf16* __restrict__ cTG, bf16* __restrict__ OC) {
  __shared__ bf16 Kls[128 * 128];     // 32KB
  __shared__ bf16 Cls[2][16 * 128];   // 4KB x2
  __shared__ bf16 Pls[8][16 * 128];   // 4KB per wave

  int lin = blockIdx.x;               // 0..511
  int v = lin >> 8, u = lin & 255;
  int qt = v ? (u >> 1) : (127 - (u >> 1));
  int hg = u & 1, b = v;
  int q0 = qt * 16;
  int nt = qt / 8 + 1;
  int tid = threadIdx.x;
  int w = tid >> 6, lane = tid & 63;
  int g = lane >> 4, cc = lane & 15;
  int h = hg * 8 + w;
  char* pbase = reinterpret_cast<char*>(&Pls[w][0]);

  bf16x8 kst[4];
  auto load_k = [&](int k0) {
#pragma unroll
    for (int i = 0; i < 4; i++) {
      int id = w * 4 + i;
      int key = id * 4 + (lane >> 4);
      int sg = (lane & 15) ^ ((id >> 1) & 15);
      kst[i] = *reinterpret_cast<const bf16x8*>(
          KcG + (((size_t)(b * S + k0 + key)) << 7) + sg * 8);
    }
  };
  auto write_k = [&]() {
#pragma unroll
    for (int i = 0; i < 4; i++) {
      int id = w * 4 + i;
      *reinterpret_cast<bf16x8*>(&Kls[(id * 64 + lane) * 8]) = kst[i];
    }
  };
  auto stage_c = [&](int k0, int buf) {
    if (w >= 4) {
      int c = (w - 4) * 4 + (lane >> 4);
      int sg = (lane & 15) ^ c;
      gload_lds16(cTG + (size_t)(b * 16 + c) * S + k0 + sg * 8,
                  &Cls[buf][(w - 4) * 512]);
    }
  };

  bf16x8 aq[3];
  const bf16* qp = Qp + (size_t)((b * 16 + h) * 2048 + q0 + cc) * 96;
#pragma unroll
  for (int kk = 0; kk < 3; kk++)
    aq[kk] = *reinterpret_cast<const bf16x8*>(qp + kk * 32 + g * 8);

  stage_c(0, 0);
  __builtin_amdgcn_sched_barrier(0);
  load_k(0);
  VMWAIT0;
  write_k();
  if (nt > 1) {
    stage_c(128, 1);
    __builtin_amdgcn_sched_barrier(0);
    load_k(128);
  }
  LGWAIT0;
  __builtin_amdgcn_s_barrier();
  __builtin_amdgcn_sched_barrier(0);

  bf16x8 ones;
#pragma unroll
  for (int j = 0; j < 8; j++) ones[j] = (bf16)1.f;

  f32x4 oc = {}, ls = {};

#pragma unroll 1
  for (int kt = 0; kt < nt; kt++) {
    int cur = kt & 1;
    int k0 = kt * 128;
    f32x4 sacc[8] = {};
    __builtin_amdgcn_s_setprio(1);
#pragma unroll
    for (int kk = 0; kk < 3; kk++)
#pragma unroll
      for (int ntb = 0; ntb < 8; ntb++) {
        int key = cc * 8 + ntb;
        bf16x8 bk = *reinterpret_cast<const bf16x8*>(
            &Kls[(key * 16 + ((kk * 4 + g) ^ cc)) * 8]);
        sacc[ntb] = __builtin_amdgcn_mfma_f32_16x16x32_bf16(aq[kk], bk, sacc[ntb], 0, 0, 0);
      }
    __builtin_amdgcn_s_setprio(0);

    bool diag = (kt == nt - 1);
#pragma unroll
    for (int r = 0; r < 4; r++) {
      bf16x8 pk;
#pragma unroll
      for (int ntb = 0; ntb < 8; ntb++) {
        float x = sacc[ntb][r];
        if (diag) {
          int qr = q0 + g * 4 + r, kc = k0 + cc * 8 + ntb;
          if (kc > qr) x = -1e30f;
        }
        pk[ntb] = (bf16)__builtin_amdgcn_exp2f(x);
      }
      int q = g * 4 + r;
      *reinterpret_cast<bf16x8*>(pbase + (q * 16 + (cc ^ (q & 7))) * 16) = pk;
    }
    LGWAIT0;
    __builtin_amdgcn_s_setprio(1);
#pragma unroll
    for (int kk2 = 0; kk2 < 4; kk2++) {
      bf16x8 pa = *reinterpret_cast<const bf16x8*>(
          pbase + (cc * 16 + ((kk2 * 4 + g) ^ (cc & 7))) * 16);
      bf16x8 bv = *reinterpret_cast<const bf16x8*>(
          &Cls[cur][(cc * 16 + ((kk2 * 4 + g) ^ cc)) * 8]);
      oc = __builtin_amdgcn_mfma_f32_16x16x32_bf16(pa, bv, oc, 0, 0, 0);
      ls = __builtin_amdgcn_mfma_f32_16x16x32_bf16(pa, ones, ls, 0, 0, 0);
    }
    __builtin_amdgcn_s_setprio(0);

    if (kt + 1 < nt) {
      __builtin_amdgcn_s_barrier();
      __builtin_amdgcn_sched_barrier(0);
      VMWAIT0;
      write_k();
      if (kt + 2 < nt) {
        stage_c((kt + 2) * 128, cur);
        __builtin_amdgcn_sched_barrier(0);
        load_k((kt + 2) * 128);
      }
      LGWAIT0;
      __builtin_amdgcn_s_barrier();
      __builtin_amdgcn_sched_barrier(0);
    }
  }

#pragma unroll
  for (int r = 0; r < 4; r++) {
    size_t t = (size_t)b * S + q0 + g * 4 + r;
    OC[t * 256 + h * 16 + cc] = (bf16)(oc[r] / ls[r]);
  }
}

// ---------------- host ----------------
extern "C" void kernel_launch(void* const* d_in, const int* in_sizes, int n_in,
                              void* d_out, int out_size, void* d_ws, size_t ws_size,
                              hipStream_t stream) {
  const float* inputs    = (const float*)d_in[0];
  const int*   pos_ids   = (const int*)d_in[1];
  const float* Wq_down   = (const float*)d_in[3];
  const float* q_norm_w  = (const float*)d_in[4];
  const float* Wq_up     = (const float*)d_in[5];
  const float* Wkv_down  = (const float*)d_in[6];
  const float* kv_norm_w = (const float*)d_in[7];
  const float* Wkv_up    = (const float*)d_in[8];
  const float* Wout      = (const float*)d_in[9];
  float* out = (float*)d_out;

  char* ws = (char*)d_ws;
  size_t off = 0;
  auto alloc = [&](size_t bytes) -> void* {
    void* p = ws + off;
    off += (bytes + 255) & ~(size_t)255;
    return p;
  };

  bf16*  in_bf = (bf16*)alloc((size_t)T * D * 2);
  bf16*  WdT   = (bf16*)alloc((size_t)NDNP * D * 2);
  bf16*  WqxT  = (bf16*)alloc((size_t)NQX * DC_Q * 2);
  bf16*  W2T   = (bf16*)alloc((size_t)D * 256 * 2);
  float* cqkv  = (float*)alloc((size_t)T * NDNP * 4);
  bf16*  cqn   = (bf16*)alloc((size_t)T * DC_Q * 2);
  bf16*  KcG   = (bf16*)alloc((size_t)T * 128 * 2);
  bf16*  cTG   = (bf16*)alloc((size_t)B * 16 * S * 2);
  bf16*  Qp    = (bf16*)alloc((size_t)B * H * S * 96 * 2);
  bf16*  OC    = (bf16*)alloc((size_t)T * H * 16 * 2);
  float* cos_t = (float*)alloc((size_t)S * 32 * 4);
  float* sin_t = (float*)alloc((size_t)S * 32 * 4);

  prologue_kernel<<<10160, 256, 0, stream>>>(
      inputs, Wq_down, Wq_up, Wkv_down, Wkv_up, Wout,
      in_bf, WdT, WqxT, W2T, cos_t, sin_t);

  gemm_bt_kernel<float, 0><<<dim3(NDNP / 128, T / 64), 256, 0, stream>>>(
      in_bf, WdT, cqkv, T, NDNP, D);
  norm_kv_kernel<<<T / 4, 256, 0, stream>>>(
      cqkv, q_norm_w, kv_norm_w, pos_ids, cos_t, sin_t, cqn, KcG, cTG);
  gemm_bt_kernel<bf16, 1><<<dim3(NQX / 128, T / 64), 256, 0, stream>>>(
      cqn, WqxT, (bf16*)nullptr, T, NQX, DC_Q, pos_ids, cos_t, sin_t, Qp);
  attn_kernel<<<512, 512, 0, stream>>>(Qp, KcG, cTG, OC);
  gemm_bt_kernel<float, 0><<<dim3(D / 128, T / 64), 256, 0, stream>>>(
      OC, W2T, out, T, D, 256);
}

// Round 17
// 135.963 us; speedup vs baseline: 1.2269x; 1.0038x over previous
//
#include <hip/hip_runtime.h>

typedef __bf16 bf16;
typedef __bf16 bf16x8 __attribute__((ext_vector_type(8)));
typedef __bf16 bf16x4 __attribute__((ext_vector_type(4)));
typedef float f32x4 __attribute__((ext_vector_type(4)));

constexpr int D = 2048, H = 16, DPH = 128, DR = 64, DC_KV = 16, DC_Q = 512;
constexpr int QHD = 192, MEG = 256, B = 2, S = 2048;
constexpr int T = B * S;
constexpr int NDNP = 640;   // fused down-proj width (512 q + 80 kv), padded to x128
constexpr int NQX = 1280;   // q gemm width: 256 absorbed qc + 1024 rope
constexpr float EPS = 1e-7f;
constexpr float KSC = 0.104124247f;  // (1/sqrt(192)) * log2(e), folded into Qp

static __device__ __forceinline__ bf16x8 zero8() {
  bf16x8 v;
#pragma unroll
  for (int j = 0; j < 8; j++) v[j] = (bf16)0.f;
  return v;
}

static __device__ __forceinline__ void gload_lds16(const bf16* g, bf16* l) {
  __builtin_amdgcn_global_load_lds(
      (const __attribute__((address_space(1))) unsigned int*)g,
      (__attribute__((address_space(3))) unsigned int*)l, 16, 0, 0);
}

#define LGWAIT0 do { asm volatile("s_waitcnt lgkmcnt(0)" ::: "memory"); __builtin_amdgcn_sched_barrier(0); } while (0)
#define VMWAIT0 do { asm volatile("s_waitcnt vmcnt(0)" ::: "memory"); __builtin_amdgcn_sched_barrier(0); } while (0)

// ================= mega prologue: all input-independent prep in ONE launch =================
// All write regions are pairwise DISJOINT (no inter-block ordering needed):
// blocks [0,8192)      : cast inputs f32 -> in_bf
// blocks [8192,8240)   : zero WdT pad rows [592,640)  (transposes never touch these)
// blocks [8240,9264)   : transpose Wq_down -> WdT rows [0,512)
// blocks [9264,9456)   : transpose Wkv_down -> WdT rows [512,592)
// blocks [9456,9520)   : prep_w3 -> WqxT rows [0,256)
// blocks [9520,9648)   : prep_wrope -> WqxT rows [256,1280)
// blocks [9648,9904)   : prep_w2 -> W2T
// blocks [9904,10160)  : rope table (f32 — matches the f32 jnp reference; f64 trig
//                        was a ~35us software-sequence tail)
__global__ __launch_bounds__(256) void prologue_kernel(
    const float* __restrict__ inputs, const float* __restrict__ Wq_down,
    const float* __restrict__ Wq_up, const float* __restrict__ Wkv_down,
    const float* __restrict__ Wkv_up, const float* __restrict__ Wout,
    bf16* __restrict__ in_bf, bf16* __restrict__ WdT, bf16* __restrict__ WqxT,
    bf16* __restrict__ W2T, float* __restrict__ cos_t, float* __restrict__ sin_t) {
  __shared__ float smem[64 * 65];
  int bid = blockIdx.x;
  int tid = threadIdx.x;

  if (bid < 8192) {                       // ---- cast ----
    int i = (bid * 256 + tid) * 4;
    float4 v = *reinterpret_cast<const float4*>(inputs + i);
    bf16x4 o;
    o[0] = (bf16)v.x; o[1] = (bf16)v.y; o[2] = (bf16)v.z; o[3] = (bf16)v.w;
    *reinterpret_cast<bf16x4*>(in_bf + i) = o;
  } else if (bid < 8240) {                // ---- zero WdT pad rows only ----
    size_t i = (size_t)592 * D + ((size_t)(bid - 8192) * 256 + tid) * 8;
    *reinterpret_cast<bf16x8*>(WdT + i) = zero8();
  } else if (bid < 9456) {                // ---- transposes ----
    const float* src; bf16* dst; int K, N, k0, n0;
    if (bid < 9264) {
      int lb = bid - 8240;
      src = Wq_down; dst = WdT; K = D; N = DC_Q;
      k0 = (lb >> 4) * 32; n0 = (lb & 15) * 32;
    } else {
      int lb = bid - 9264;
      src = Wkv_down; dst = WdT + (size_t)DC_Q * D; K = D; N = 80;
      k0 = (lb / 3) * 32; n0 = (lb % 3) * 32;
    }
    float (*tile)[33] = (float(*)[33])smem;
#pragma unroll
    for (int e = tid; e < 1024; e += 256) {
      int i = e >> 5, j = e & 31;
      int k = k0 + i, n = n0 + j;
      tile[i][j] = (k < K && n < N) ? src[(size_t)k * N + n] : 0.f;
    }
    __syncthreads();
#pragma unroll
    for (int e = tid; e < 1024; e += 256) {
      int jj = e >> 5, ii = e & 31;
      int n = n0 + jj, k = k0 + ii;
      if (k < K && n < N) dst[(size_t)n * D + k] = (bf16)tile[ii][jj];
    }
  } else if (bid < 9520) {                // ---- prep_w3 ----
    int lb = bid - 9456;
    int h = lb >> 2, k0 = (lb & 3) * 128;
    float (*wk)[16] = (float(*)[16])smem;
#pragma unroll
    for (int e = tid; e < 2048; e += 256) {
      int v = e >> 4, c = e & 15;
      wk[v][c] = Wkv_up[(size_t)c * (H * MEG) + h * MEG + v];
    }
    __syncthreads();
    if (tid < 128) {
      int k = k0 + tid;
      float acc[16] = {};
      for (int v = 0; v < 128; v++) {
        float wq = Wq_up[(size_t)k * (H * QHD) + h * QHD + v];
#pragma unroll
        for (int c = 0; c < 16; c++) acc[c] += wk[v][c] * wq;
      }
#pragma unroll
      for (int c = 0; c < 16; c++)
        WqxT[(size_t)(h * 16 + c) * DC_Q + k] = (bf16)acc[c];
    }
  } else if (bid < 9648) {                // ---- prep_wrope ----
    int lb = bid - 9520;
    int h = lb >> 3, k0 = (lb & 7) * 64;
    float (*tile)[65] = (float(*)[65])smem;
#pragma unroll
    for (int p = 0; p < 16; p++) {
      int kk = p * 4 + (tid >> 6), j = tid & 63;
      tile[kk][j] = Wq_up[(size_t)(k0 + kk) * (H * QHD) + h * QHD + 128 + j];
    }
    __syncthreads();
#pragma unroll
    for (int p = 0; p < 16; p++) {
      int n = p * 4 + (tid >> 6), k = tid & 63;
      WqxT[(size_t)(256 + h * 64 + n) * DC_Q + k0 + k] = (bf16)tile[k][n];
    }
  } else if (bid < 9904) {                // ---- prep_w2 ----
    int lb = bid - 9648;
    int h = lb >> 4, d0 = (lb & 15) * 128;
    float (*wv)[16] = (float(*)[16])smem;
#pragma unroll
    for (int e = tid; e < 2048; e += 256) {
      int v = e >> 4, c = e & 15;
      wv[v][c] = Wkv_up[(size_t)c * (H * MEG) + h * MEG + 128 + v];
    }
    __syncthreads();
    if (tid < 128) {
      int d = d0 + tid;
      float acc[16] = {};
      for (int v = 0; v < 128; v++) {
        float wo = Wout[(size_t)(h * 128 + v) * D + d];
#pragma unroll
        for (int c = 0; c < 16; c++) acc[c] += wv[v][c] * wo;
      }
      bf16x8 o0, o1;
#pragma unroll
      for (int c = 0; c < 8; c++) { o0[c] = (bf16)acc[c]; o1[c] = (bf16)acc[8 + c]; }
      *reinterpret_cast<bf16x8*>(&W2T[(size_t)d * 256 + h * 16]) = o0;
      *reinterpret_cast<bf16x8*>(&W2T[(size_t)d * 256 + h * 16 + 8]) = o1;
    }
  } else {                                // ---- rope table (f32, matches jnp f32 ref) ----
    int i = (bid - 9904) * 256 + tid;     // over S*32
    int pos = i >> 5, j = i & 31;
    float invf = 1.0f / powf(10000.0f, (float)(2 * j) / 64.0f);
    float a = (float)pos * invf;
    cos_t[i] = cosf(a);
    sin_t[i] = sinf(a);
  }
}

// ======== merged rmsnorm(q) + kv prep: 1 wave per token ========
__global__ __launch_bounds__(256) void norm_kv_kernel(
    const float* __restrict__ cqkv, const float* __restrict__ qw,
    const float* __restrict__ kvw, const int* __restrict__ pos_ids,
    const float* __restrict__ cos_t, const float* __restrict__ sin_t,
    bf16* __restrict__ cqn, bf16* __restrict__ KcG, bf16* __restrict__ cTG) {
  int w = threadIdx.x >> 6, lane = threadIdx.x & 63;
  int t = blockIdx.x * 4 + w;
  int b = t >> 11, s = t & (S - 1);
  const float* x = cqkv + (size_t)t * NDNP;
  // ---- q rmsnorm over [0,512) ----
  float4 v0 = *reinterpret_cast<const float4*>(x + lane * 8);
  float4 v1 = *reinterpret_cast<const float4*>(x + lane * 8 + 4);
  float ss = v0.x * v0.x + v0.y * v0.y + v0.z * v0.z + v0.w * v0.w +
             v1.x * v1.x + v1.y * v1.y + v1.z * v1.z + v1.w * v1.w;
#pragma unroll
  for (int off = 32; off; off >>= 1) ss += __shfl_xor(ss, off);
  float r = rsqrtf(ss / (float)DC_Q + EPS);
  const float* wp = qw + lane * 8;
  float vv[8] = {v0.x, v0.y, v0.z, v0.w, v1.x, v1.y, v1.z, v1.w};
  bf16x8 o;
#pragma unroll
  for (int j = 0; j < 8; j++) o[j] = (bf16)(vv[j] * r * wp[j]);
  *reinterpret_cast<bf16x8*>(cqn + (size_t)t * DC_Q + lane * 8) = o;
  // ---- kv prep over [512,592) ----
  const float* xk = x + DC_Q;
  float vk = (lane < 16) ? xk[lane] : 0.f;
  float sk = vk * vk;
#pragma unroll
  for (int off = 1; off < 16; off <<= 1) sk += __shfl_xor(sk, off);
  float rk = rsqrtf(sk / 16.f + EPS);
  bf16* krow = KcG + ((size_t)t << 7);
  if (lane < 16) {
    bf16 cn = (bf16)(vk * rk * kvw[lane]);
    krow[64 + lane] = cn;
    cTG[(size_t)(b * 16 + lane) * S + s] = cn;
  } else {
    krow[64 + lane] = (bf16)0.f;   // dims 80..127 zero
  }
  if (lane < 32) {
    int j = lane;
    int pos = pos_ids[t];
    float cf = cos_t[pos * 32 + j], sf = sin_t[pos * 32 + j];
    float x0 = xk[16 + 2 * j], x1 = xk[16 + 2 * j + 1];
    krow[j]      = (bf16)(x0 * cf - x1 * sf);
    krow[32 + j] = (bf16)(x1 * cf + x0 * sf);
  }
}

// ---------------- bf16 MFMA GEMM, 64x128 tile, dbuf + counted vmcnt ----------------
// EPI 0: plain C write. EPI 1: q-path epilogue -> writes Qp (RoPE via lane-pair shfl,
// KSC fold); qc tiles (n0<256) write Qp[64+c] and zero [80+c].
template <typename OutT, int EPI>
__global__ __launch_bounds__(256) void gemm_bt_kernel(
    const bf16* __restrict__ A, const bf16* __restrict__ Bt,
    OutT* __restrict__ C, int M, int N, int K,
    const int* __restrict__ pos_ids = nullptr,
    const float* __restrict__ cos_t = nullptr,
    const float* __restrict__ sin_t = nullptr,
    bf16* __restrict__ Qp = nullptr) {
  __shared__ bf16 As[2][64 * 64];
  __shared__ bf16 Bs[2][128 * 64];
  int tid = threadIdx.x;
  int wid = tid >> 6, lane = tid & 63;
  int g = lane >> 4, c = lane & 15;
  int nbx = gridDim.x;                 // N / 128
  int lin = blockIdx.y * nbx + blockIdx.x;
  int cpx = (nbx * gridDim.y) >> 3;    // grid % 8 == 0 for all uses
  int swz = (lin & 7) * cpx + (lin >> 3);
  int m0 = (swz / nbx) * 64, n0 = (swz % nbx) * 128;
  int lrow8 = tid >> 3, lslot = tid & 7;

  auto stage = [&](int kt, int buf) {
    int k0 = kt << 6;
#pragma unroll
    for (int r = 0; r < 2; r++) {
      int row = r * 32 + lrow8;
      int sslot = lslot ^ (row & 7);
      gload_lds16(A + (size_t)(m0 + row) * K + k0 + sslot * 8, &As[buf][row * 64 + lslot * 8]);
    }
#pragma unroll
    for (int r = 0; r < 4; r++) {
      int row = r * 32 + lrow8;
      int sslot = lslot ^ (row & 7);
      gload_lds16(Bt + (size_t)(n0 + row) * K + k0 + sslot * 8, &Bs[buf][row * 64 + lslot * 8]);
    }
  };

  f32x4 acc[4][2] = {};
  int nk = K >> 6;
  stage(0, 0);
  __builtin_amdgcn_sched_barrier(0);
  for (int kt = 0; kt < nk; kt++) {
    int cur = kt & 1;
    __builtin_amdgcn_s_barrier();
    __builtin_amdgcn_sched_barrier(0);
    if (kt + 1 < nk) {
      stage(kt + 1, cur ^ 1);
      asm volatile("s_waitcnt vmcnt(6)" ::: "memory");
    } else {
      asm volatile("s_waitcnt vmcnt(0)" ::: "memory");
    }
    __builtin_amdgcn_sched_barrier(0);
    __builtin_amdgcn_s_barrier();
    __builtin_amdgcn_sched_barrier(0);
#pragma unroll
    for (int kk = 0; kk < 2; kk++) {
      bf16x8 af[4], bfr[2];
#pragma unroll
      for (int mi = 0; mi < 4; mi++) {
        int row = mi * 16 + c;
        int sl = (kk * 4 + g) ^ (row & 7);
        af[mi] = *reinterpret_cast<const bf16x8*>(&As[cur][row * 64 + sl * 8]);
      }
#pragma unroll
      for (int ni = 0; ni < 2; ni++) {
        int row = wid * 32 + ni * 16 + c;
        int sl = (kk * 4 + g) ^ (row & 7);
        bfr[ni] = *reinterpret_cast<const bf16x8*>(&Bs[cur][row * 64 + sl * 8]);
      }
#pragma unroll
      for (int mi = 0; mi < 4; mi++)
#pragma unroll
        for (int ni = 0; ni < 2; ni++)
          acc[mi][ni] = __builtin_amdgcn_mfma_f32_16x16x32_bf16(af[mi], bfr[ni], acc[mi][ni], 0, 0, 0);
    }
  }

  if constexpr (EPI == 0) {
#pragma unroll
    for (int mi = 0; mi < 4; mi++)
#pragma unroll
      for (int ni = 0; ni < 2; ni++)
#pragma unroll
        for (int r = 0; r < 4; r++) {
          int row = m0 + mi * 16 + g * 4 + r;
          int col = n0 + wid * 32 + ni * 16 + c;
          C[(size_t)row * N + col] = (OutT)acc[mi][ni][r];
        }
  } else {
    // q-path epilogue: write absorbed Q directly
    bool ropeTile = (n0 >= 256);
#pragma unroll
    for (int mi = 0; mi < 4; mi++)
#pragma unroll
      for (int r = 0; r < 4; r++) {
        int row = m0 + mi * 16 + g * 4 + r;       // token t
        int b = row >> 11, s = row & (S - 1);
#pragma unroll
        for (int ni = 0; ni < 2; ni++) {
          int col = n0 + wid * 32 + ni * 16 + c;
          float val = acc[mi][ni][r];
          if (!ropeTile) {
            int h = col >> 4, cq = col & 15;
            bf16* qrow = Qp + (size_t)((b * 16 + h) * 2048 + s) * 96;
            qrow[64 + cq] = (bf16)(val * KSC);
            qrow[80 + cq] = (bf16)0.f;
          } else {
            int colr = col - 256;
            int h = colr >> 6, jj = colr & 63, j = jj >> 1;
            int pos = pos_ids[row];
            float cf = cos_t[pos * 32 + j], sf = sin_t[pos * 32 + j];
            float other = __shfl_xor(val, 1);
            bf16* qrow = Qp + (size_t)((b * 16 + h) * 2048 + s) * 96;
            if ((c & 1) == 0) {
              qrow[j] = (bf16)((val * cf - other * sf) * KSC);
            } else {
              qrow[32 + j] = (bf16)((val * cf + other * sf) * KSC);
            }
          }
        }
      }
  }
}

// ---------------- absorbed flash attention, single-Kls reg-staged, 2 blocks/CU ----------------
__global__ __launch_bounds__(512, 4) void attn_kernel(
    const bf16* __restrict__ Qp, const bf16* __restrict__ KcG,
    const bf16* __restrict__ cTG, bf16* __restrict__ OC) {
  __shared__ bf16 Kls[128 * 128];     // 32KB
  __shared__ bf16 Cls[2][16 * 128];   // 4KB x2
  __shared__ bf16 Pls[8][16 * 128];   // 4KB per wave

  int lin = blockIdx.x;               // 0..511
  int v = lin >> 8, u = lin & 255;
  int qt = v ? (u >> 1) : (127 - (u >> 1));
  int hg = u & 1, b = v;
  int q0 = qt * 16;
  int nt = qt / 8 + 1;
  int tid = threadIdx.x;
  int w = tid >> 6, lane = tid & 63;
  int g = lane >> 4, cc = lane & 15;
  int h = hg * 8 + w;
  char* pbase = reinterpret_cast<char*>(&Pls[w][0]);

  bf16x8 kst[4];
  auto load_k = [&](int k0) {
#pragma unroll
    for (int i = 0; i < 4; i++) {
      int id = w * 4 + i;
      int key = id * 4 + (lane >> 4);
      int sg = (lane & 15) ^ ((id >> 1) & 15);
      kst[i] = *reinterpret_cast<const bf16x8*>(
          KcG + (((size_t)(b * S + k0 + key)) << 7) + sg * 8);
    }
  };
  auto write_k = [&]() {
#pragma unroll
    for (int i = 0; i < 4; i++) {
      int id = w * 4 + i;
      *reinterpret_cast<bf16x8*>(&Kls[(id * 64 + lane) * 8]) = kst[i];
    }
  };
  auto stage_c = [&](int k0, int buf) {
    if (w >= 4) {
      int c = (w - 4) * 4 + (lane >> 4);
      int sg = (lane & 15) ^ c;
      gload_lds16(cTG + (size_t)(b * 16 + c) * S + k0 + sg * 8,
                  &Cls[buf][(w - 4) * 512]);
    }
  };

  bf16x8 aq[3];
  const bf16* qp = Qp + (size_t)((b * 16 + h) * 2048 + q0 + cc) * 96;
#pragma unroll
  for (int kk = 0; kk < 3; kk++)
    aq[kk] = *reinterpret_cast<const bf16x8*>(qp + kk * 32 + g * 8);

  stage_c(0, 0);
  __builtin_amdgcn_sched_barrier(0);
  load_k(0);
  VMWAIT0;
  write_k();
  if (nt > 1) {
    stage_c(128, 1);
    __builtin_amdgcn_sched_barrier(0);
    load_k(128);
  }
  LGWAIT0;
  __builtin_amdgcn_s_barrier();
  __builtin_amdgcn_sched_barrier(0);

  bf16x8 ones;
#pragma unroll
  for (int j = 0; j < 8; j++) ones[j] = (bf16)1.f;

  f32x4 oc = {}, ls = {};

#pragma unroll 1
  for (int kt = 0; kt < nt; kt++) {
    int cur = kt & 1;
    int k0 = kt * 128;
    f32x4 sacc[8] = {};
    __builtin_amdgcn_s_setprio(1);
#pragma unroll
    for (int kk = 0; kk < 3; kk++)
#pragma unroll
      for (int ntb = 0; ntb < 8; ntb++) {
        int key = cc * 8 + ntb;
        bf16x8 bk = *reinterpret_cast<const bf16x8*>(
            &Kls[(key * 16 + ((kk * 4 + g) ^ cc)) * 8]);
        sacc[ntb] = __builtin_amdgcn_mfma_f32_16x16x32_bf16(aq[kk], bk, sacc[ntb], 0, 0, 0);
      }
    __builtin_amdgcn_s_setprio(0);

    bool diag = (kt == nt - 1);
#pragma unroll
    for (int r = 0; r < 4; r++) {
      bf16x8 pk;
#pragma unroll
      for (int ntb = 0; ntb < 8; ntb++) {
        float x = sacc[ntb][r];
        if (diag) {
          int qr = q0 + g * 4 + r, kc = k0 + cc * 8 + ntb;
          if (kc > qr) x = -1e30f;
        }
        pk[ntb] = (bf16)__builtin_amdgcn_exp2f(x);
      }
      int q = g * 4 + r;
      *reinterpret_cast<bf16x8*>(pbase + (q * 16 + (cc ^ (q & 7))) * 16) = pk;
    }
    LGWAIT0;
    __builtin_amdgcn_s_setprio(1);
#pragma unroll
    for (int kk2 = 0; kk2 < 4; kk2++) {
      bf16x8 pa = *reinterpret_cast<const bf16x8*>(
          pbase + (cc * 16 + ((kk2 * 4 + g) ^ (cc & 7))) * 16);
      bf16x8 bv = *reinterpret_cast<const bf16x8*>(
          &Cls[cur][(cc * 16 + ((kk2 * 4 + g) ^ cc)) * 8]);
      oc = __builtin_amdgcn_mfma_f32_16x16x32_bf16(pa, bv, oc, 0, 0, 0);
      ls = __builtin_amdgcn_mfma_f32_16x16x32_bf16(pa, ones, ls, 0, 0, 0);
    }
    __builtin_amdgcn_s_setprio(0);

    if (kt + 1 < nt) {
      __builtin_amdgcn_s_barrier();
      __builtin_amdgcn_sched_barrier(0);
      VMWAIT0;
      write_k();
      if (kt + 2 < nt) {
        stage_c((kt + 2) * 128, cur);
        __builtin_amdgcn_sched_barrier(0);
        load_k((kt + 2) * 128);
      }
      LGWAIT0;
      __builtin_amdgcn_s_barrier();
      __builtin_amdgcn_sched_barrier(0);
    }
  }

#pragma unroll
  for (int r = 0; r < 4; r++) {
    size_t t = (size_t)b * S + q0 + g * 4 + r;
    OC[t * 256 + h * 16 + cc] = (bf16)(oc[r] / ls[r]);
  }
}

// ---------------- host ----------------
extern "C" void kernel_launch(void* const* d_in, const int* in_sizes, int n_in,
                              void* d_out, int out_size, void* d_ws, size_t ws_size,
                              hipStream_t stream) {
  const float* inputs    = (const float*)d_in[0];
  const int*   pos_ids   = (const int*)d_in[1];
  const float* Wq_down   = (const float*)d_in[3];
  const float* q_norm_w  = (const float*)d_in[4];
  const float* Wq_up     = (const float*)d_in[5];
  const float* Wkv_down  = (const float*)d_in[6];
  const float* kv_norm_w = (const float*)d_in[7];
  const float* Wkv_up    = (const float*)d_in[8];
  const float* Wout      = (const float*)d_in[9];
  float* out = (float*)d_out;

  char* ws = (char*)d_ws;
  size_t off = 0;
  auto alloc = [&](size_t bytes) -> void* {
    void* p = ws + off;
    off += (bytes + 255) & ~(size_t)255;
    return p;
  };

  bf16*  in_bf = (bf16*)alloc((size_t)T * D * 2);
  bf16*  WdT   = (bf16*)alloc((size_t)NDNP * D * 2);
  bf16*  WqxT  = (bf16*)alloc((size_t)NQX * DC_Q * 2);
  bf16*  W2T   = (bf16*)alloc((size_t)D * 256 * 2);
  float* cqkv  = (float*)alloc((size_t)T * NDNP * 4);
  bf16*  cqn   = (bf16*)alloc((size_t)T * DC_Q * 2);
  bf16*  KcG   = (bf16*)alloc((size_t)T * 128 * 2);
  bf16*  cTG   = (bf16*)alloc((size_t)B * 16 * S * 2);
  bf16*  Qp    = (bf16*)alloc((size_t)B * H * S * 96 * 2);
  bf16*  OC    = (bf16*)alloc((size_t)T * H * 16 * 2);
  float* cos_t = (float*)alloc((size_t)S * 32 * 4);
  float* sin_t = (float*)alloc((size_t)S * 32 * 4);

  prologue_kernel<<<10160, 256, 0, stream>>>(
      inputs, Wq_down, Wq_up, Wkv_down, Wkv_up, Wout,
      in_bf, WdT, WqxT, W2T, cos_t, sin_t);

  gemm_bt_kernel<float, 0><<<dim3(NDNP / 128, T / 64), 256, 0, stream>>>(
      in_bf, WdT, cqkv, T, NDNP, D);
  norm_kv_kernel<<<T / 4, 256, 0, stream>>>(
      cqkv, q_norm_w, kv_norm_w, pos_ids, cos_t, sin_t, cqn, KcG, cTG);
  gemm_bt_kernel<bf16, 1><<<dim3(NQX / 128, T / 64), 256, 0, stream>>>(
      cqn, WqxT, (bf16*)nullptr, T, NQX, DC_Q, pos_ids, cos_t, sin_t, Qp);
  attn_kernel<<<512, 512, 0, stream>>>(Qp, KcG, cTG, OC);
  gemm_bt_kernel<float, 0><<<dim3(D / 128, T / 64), 256, 0, stream>>>(
      OC, W2T, out, T, D, 256);
}

// Round 18
// 133.075 us; speedup vs baseline: 1.2535x; 1.0217x over previous
//
#include <hip/hip_runtime.h>

typedef __bf16 bf16;
typedef __bf16 bf16x8 __attribute__((ext_vector_type(8)));
typedef __bf16 bf16x4 __attribute__((ext_vector_type(4)));
typedef float f32x4 __attribute__((ext_vector_type(4)));

constexpr int D = 2048, H = 16, DPH = 128, DR = 64, DC_KV = 16, DC_Q = 512;
constexpr int QHD = 192, MEG = 256, B = 2, S = 2048;
constexpr int T = B * S;
constexpr int NDNP = 640;   // fused down-proj width (512 q + 80 kv), padded to x128
constexpr int NQX = 1280;   // q gemm width: 256 absorbed qc + 1024 rope
constexpr float EPS = 1e-7f;
constexpr float KSC = 0.104124247f;  // (1/sqrt(192)) * log2(e), folded into Qp

static __device__ __forceinline__ bf16x8 zero8() {
  bf16x8 v;
#pragma unroll
  for (int j = 0; j < 8; j++) v[j] = (bf16)0.f;
  return v;
}

static __device__ __forceinline__ void gload_lds16(const bf16* g, bf16* l) {
  __builtin_amdgcn_global_load_lds(
      (const __attribute__((address_space(1))) unsigned int*)g,
      (__attribute__((address_space(3))) unsigned int*)l, 16, 0, 0);
}

#define LGWAIT0 do { asm volatile("s_waitcnt lgkmcnt(0)" ::: "memory"); __builtin_amdgcn_sched_barrier(0); } while (0)
#define VMWAIT0 do { asm volatile("s_waitcnt vmcnt(0)" ::: "memory"); __builtin_amdgcn_sched_barrier(0); } while (0)

// ================= mega prologue: all input-independent prep in ONE launch =================
// All write regions are pairwise DISJOINT (no inter-block ordering needed):
// blocks [0,2048)      : cast inputs f32 -> in_bf (4 float4/thread, batched loads for MLP)
// blocks [2048,2096)   : zero WdT pad rows [592,640)
// blocks [2096,3120)   : transpose Wq_down -> WdT rows [0,512)
// blocks [3120,3312)   : transpose Wkv_down -> WdT rows [512,592)
// blocks [3312,3376)   : prep_w3 -> WqxT rows [0,256)  (v-loop unroll 8 for load MLP)
// blocks [3376,3504)   : prep_wrope -> WqxT rows [256,1280)
// blocks [3504,3760)   : prep_w2 -> W2T               (v-loop unroll 8 for load MLP)
// blocks [3760,4016)   : rope table (f32 — matches f32 jnp reference)
__global__ __launch_bounds__(256) void prologue_kernel(
    const float* __restrict__ inputs, const float* __restrict__ Wq_down,
    const float* __restrict__ Wq_up, const float* __restrict__ Wkv_down,
    const float* __restrict__ Wkv_up, const float* __restrict__ Wout,
    bf16* __restrict__ in_bf, bf16* __restrict__ WdT, bf16* __restrict__ WqxT,
    bf16* __restrict__ W2T, float* __restrict__ cos_t, float* __restrict__ sin_t) {
  __shared__ float smem[64 * 65];
  int bid = blockIdx.x;
  int tid = threadIdx.x;

  if (bid < 2048) {                       // ---- cast: 4 coalesced rounds, loads batched ----
    int gid = bid * 256 + tid;            // float4 index; stride 524288 between rounds
    float4 v[4];
#pragma unroll
    for (int k = 0; k < 4; k++)
      v[k] = *reinterpret_cast<const float4*>(inputs + ((size_t)(gid + k * 524288)) * 4);
#pragma unroll
    for (int k = 0; k < 4; k++) {
      bf16x4 o;
      o[0] = (bf16)v[k].x; o[1] = (bf16)v[k].y; o[2] = (bf16)v[k].z; o[3] = (bf16)v[k].w;
      *reinterpret_cast<bf16x4*>(in_bf + ((size_t)(gid + k * 524288)) * 4) = o;
    }
  } else if (bid < 2096) {                // ---- zero WdT pad rows only ----
    size_t i = (size_t)592 * D + ((size_t)(bid - 2048) * 256 + tid) * 8;
    *reinterpret_cast<bf16x8*>(WdT + i) = zero8();
  } else if (bid < 3312) {                // ---- transposes ----
    const float* src; bf16* dst; int K, N, k0, n0;
    if (bid < 3120) {
      int lb = bid - 2096;
      src = Wq_down; dst = WdT; K = D; N = DC_Q;
      k0 = (lb >> 4) * 32; n0 = (lb & 15) * 32;
    } else {
      int lb = bid - 3120;
      src = Wkv_down; dst = WdT + (size_t)DC_Q * D; K = D; N = 80;
      k0 = (lb / 3) * 32; n0 = (lb % 3) * 32;
    }
    float (*tile)[33] = (float(*)[33])smem;
#pragma unroll
    for (int e = tid; e < 1024; e += 256) {
      int i = e >> 5, j = e & 31;
      int k = k0 + i, n = n0 + j;
      tile[i][j] = (k < K && n < N) ? src[(size_t)k * N + n] : 0.f;
    }
    __syncthreads();
#pragma unroll
    for (int e = tid; e < 1024; e += 256) {
      int jj = e >> 5, ii = e & 31;
      int n = n0 + jj, k = k0 + ii;
      if (k < K && n < N) dst[(size_t)n * D + k] = (bf16)tile[ii][jj];
    }
  } else if (bid < 3376) {                // ---- prep_w3 ----
    int lb = bid - 3312;
    int h = lb >> 2, k0 = (lb & 3) * 128;
    float (*wk)[16] = (float(*)[16])smem;
#pragma unroll
    for (int e = tid; e < 2048; e += 256) {
      int v = e >> 4, c = e & 15;
      wk[v][c] = Wkv_up[(size_t)c * (H * MEG) + h * MEG + v];
    }
    __syncthreads();
    if (tid < 128) {
      int k = k0 + tid;
      float acc[16] = {};
#pragma unroll 8
      for (int v = 0; v < 128; v++) {
        float wq = Wq_up[(size_t)k * (H * QHD) + h * QHD + v];
#pragma unroll
        for (int c = 0; c < 16; c++) acc[c] += wk[v][c] * wq;
      }
#pragma unroll
      for (int c = 0; c < 16; c++)
        WqxT[(size_t)(h * 16 + c) * DC_Q + k] = (bf16)acc[c];
    }
  } else if (bid < 3504) {                // ---- prep_wrope ----
    int lb = bid - 3376;
    int h = lb >> 3, k0 = (lb & 7) * 64;
    float (*tile)[65] = (float(*)[65])smem;
#pragma unroll
    for (int p = 0; p < 16; p++) {
      int kk = p * 4 + (tid >> 6), j = tid & 63;
      tile[kk][j] = Wq_up[(size_t)(k0 + kk) * (H * QHD) + h * QHD + 128 + j];
    }
    __syncthreads();
#pragma unroll
    for (int p = 0; p < 16; p++) {
      int n = p * 4 + (tid >> 6), k = tid & 63;
      WqxT[(size_t)(256 + h * 64 + n) * DC_Q + k0 + k] = (bf16)tile[k][n];
    }
  } else if (bid < 3760) {                // ---- prep_w2 ----
    int lb = bid - 3504;
    int h = lb >> 4, d0 = (lb & 15) * 128;
    float (*wv)[16] = (float(*)[16])smem;
#pragma unroll
    for (int e = tid; e < 2048; e += 256) {
      int v = e >> 4, c = e & 15;
      wv[v][c] = Wkv_up[(size_t)c * (H * MEG) + h * MEG + 128 + v];
    }
    __syncthreads();
    if (tid < 128) {
      int d = d0 + tid;
      float acc[16] = {};
#pragma unroll 8
      for (int v = 0; v < 128; v++) {
        float wo = Wout[(size_t)(h * 128 + v) * D + d];
#pragma unroll
        for (int c = 0; c < 16; c++) acc[c] += wv[v][c] * wo;
      }
      bf16x8 o0, o1;
#pragma unroll
      for (int c = 0; c < 8; c++) { o0[c] = (bf16)acc[c]; o1[c] = (bf16)acc[8 + c]; }
      *reinterpret_cast<bf16x8*>(&W2T[(size_t)d * 256 + h * 16]) = o0;
      *reinterpret_cast<bf16x8*>(&W2T[(size_t)d * 256 + h * 16 + 8]) = o1;
    }
  } else {                                // ---- rope table (f32, matches jnp f32 ref) ----
    int i = (bid - 3760) * 256 + tid;     // over S*32
    int pos = i >> 5, j = i & 31;
    float invf = 1.0f / powf(10000.0f, (float)(2 * j) / 64.0f);
    float a = (float)pos * invf;
    cos_t[i] = cosf(a);
    sin_t[i] = sinf(a);
  }
}

// ======== merged rmsnorm(q) + kv prep: 1 wave per token ========
__global__ __launch_bounds__(256) void norm_kv_kernel(
    const float* __restrict__ cqkv, const float* __restrict__ qw,
    const float* __restrict__ kvw, const int* __restrict__ pos_ids,
    const float* __restrict__ cos_t, const float* __restrict__ sin_t,
    bf16* __restrict__ cqn, bf16* __restrict__ KcG, bf16* __restrict__ cTG) {
  int w = threadIdx.x >> 6, lane = threadIdx.x & 63;
  int t = blockIdx.x * 4 + w;
  int b = t >> 11, s = t & (S - 1);
  const float* x = cqkv + (size_t)t * NDNP;
  // ---- q rmsnorm over [0,512) ----
  float4 v0 = *reinterpret_cast<const float4*>(x + lane * 8);
  float4 v1 = *reinterpret_cast<const float4*>(x + lane * 8 + 4);
  float ss = v0.x * v0.x + v0.y * v0.y + v0.z * v0.z + v0.w * v0.w +
             v1.x * v1.x + v1.y * v1.y + v1.z * v1.z + v1.w * v1.w;
#pragma unroll
  for (int off = 32; off; off >>= 1) ss += __shfl_xor(ss, off);
  float r = rsqrtf(ss / (float)DC_Q + EPS);
  const float* wp = qw + lane * 8;
  float vv[8] = {v0.x, v0.y, v0.z, v0.w, v1.x, v1.y, v1.z, v1.w};
  bf16x8 o;
#pragma unroll
  for (int j = 0; j < 8; j++) o[j] = (bf16)(vv[j] * r * wp[j]);
  *reinterpret_cast<bf16x8*>(cqn + (size_t)t * DC_Q + lane * 8) = o;
  // ---- kv prep over [512,592) ----
  const float* xk = x + DC_Q;
  float vk = (lane < 16) ? xk[lane] : 0.f;
  float sk = vk * vk;
#pragma unroll
  for (int off = 1; off < 16; off <<= 1) sk += __shfl_xor(sk, off);
  float rk = rsqrtf(sk / 16.f + EPS);
  bf16* krow = KcG + ((size_t)t << 7);
  if (lane < 16) {
    bf16 cn = (bf16)(vk * rk * kvw[lane]);
    krow[64 + lane] = cn;
    cTG[(size_t)(b * 16 + lane) * S + s] = cn;
  } else {
    krow[64 + lane] = (bf16)0.f;   // dims 80..127 zero
  }
  if (lane < 32) {
    int j = lane;
    int pos = pos_ids[t];
    float cf = cos_t[pos * 32 + j], sf = sin_t[pos * 32 + j];
    float x0 = xk[16 + 2 * j], x1 = xk[16 + 2 * j + 1];
    krow[j]      = (bf16)(x0 * cf - x1 * sf);
    krow[32 + j] = (bf16)(x1 * cf + x0 * sf);
  }
}

// ---------------- bf16 MFMA GEMM, 64x128 tile, dbuf + counted vmcnt ----------------
// EPI 0: plain C write. EPI 1: q-path epilogue -> writes Qp (RoPE via lane-pair shfl,
// KSC fold); qc tiles (n0<256) write Qp[64+c] and zero [80+c].
template <typename OutT, int EPI>
__global__ __launch_bounds__(256) void gemm_bt_kernel(
    const bf16* __restrict__ A, const bf16* __restrict__ Bt,
    OutT* __restrict__ C, int M, int N, int K,
    const int* __restrict__ pos_ids = nullptr,
    const float* __restrict__ cos_t = nullptr,
    const float* __restrict__ sin_t = nullptr,
    bf16* __restrict__ Qp = nullptr) {
  __shared__ bf16 As[2][64 * 64];
  __shared__ bf16 Bs[2][128 * 64];
  int tid = threadIdx.x;
  int wid = tid >> 6, lane = tid & 63;
  int g = lane >> 4, c = lane & 15;
  int nbx = gridDim.x;                 // N / 128
  int lin = blockIdx.y * nbx + blockIdx.x;
  int cpx = (nbx * gridDim.y) >> 3;    // grid % 8 == 0 for all uses
  int swz = (lin & 7) * cpx + (lin >> 3);
  int m0 = (swz / nbx) * 64, n0 = (swz % nbx) * 128;
  int lrow8 = tid >> 3, lslot = tid & 7;

  auto stage = [&](int kt, int buf) {
    int k0 = kt << 6;
#pragma unroll
    for (int r = 0; r < 2; r++) {
      int row = r * 32 + lrow8;
      int sslot = lslot ^ (row & 7);
      gload_lds16(A + (size_t)(m0 + row) * K + k0 + sslot * 8, &As[buf][row * 64 + lslot * 8]);
    }
#pragma unroll
    for (int r = 0; r < 4; r++) {
      int row = r * 32 + lrow8;
      int sslot = lslot ^ (row & 7);
      gload_lds16(Bt + (size_t)(n0 + row) * K + k0 + sslot * 8, &Bs[buf][row * 64 + lslot * 8]);
    }
  };

  f32x4 acc[4][2] = {};
  int nk = K >> 6;
  stage(0, 0);
  __builtin_amdgcn_sched_barrier(0);
  for (int kt = 0; kt < nk; kt++) {
    int cur = kt & 1;
    __builtin_amdgcn_s_barrier();
    __builtin_amdgcn_sched_barrier(0);
    if (kt + 1 < nk) {
      stage(kt + 1, cur ^ 1);
      asm volatile("s_waitcnt vmcnt(6)" ::: "memory");
    } else {
      asm volatile("s_waitcnt vmcnt(0)" ::: "memory");
    }
    __builtin_amdgcn_sched_barrier(0);
    __builtin_amdgcn_s_barrier();
    __builtin_amdgcn_sched_barrier(0);
#pragma unroll
    for (int kk = 0; kk < 2; kk++) {
      bf16x8 af[4], bfr[2];
#pragma unroll
      for (int mi = 0; mi < 4; mi++) {
        int row = mi * 16 + c;
        int sl = (kk * 4 + g) ^ (row & 7);
        af[mi] = *reinterpret_cast<const bf16x8*>(&As[cur][row * 64 + sl * 8]);
      }
#pragma unroll
      for (int ni = 0; ni < 2; ni++) {
        int row = wid * 32 + ni * 16 + c;
        int sl = (kk * 4 + g) ^ (row & 7);
        bfr[ni] = *reinterpret_cast<const bf16x8*>(&Bs[cur][row * 64 + sl * 8]);
      }
#pragma unroll
      for (int mi = 0; mi < 4; mi++)
#pragma unroll
        for (int ni = 0; ni < 2; ni++)
          acc[mi][ni] = __builtin_amdgcn_mfma_f32_16x16x32_bf16(af[mi], bfr[ni], acc[mi][ni], 0, 0, 0);
    }
  }

  if constexpr (EPI == 0) {
#pragma unroll
    for (int mi = 0; mi < 4; mi++)
#pragma unroll
      for (int ni = 0; ni < 2; ni++)
#pragma unroll
        for (int r = 0; r < 4; r++) {
          int row = m0 + mi * 16 + g * 4 + r;
          int col = n0 + wid * 32 + ni * 16 + c;
          C[(size_t)row * N + col] = (OutT)acc[mi][ni][r];
        }
  } else {
    // q-path epilogue: write absorbed Q directly
    bool ropeTile = (n0 >= 256);
#pragma unroll
    for (int mi = 0; mi < 4; mi++)
#pragma unroll
      for (int r = 0; r < 4; r++) {
        int row = m0 + mi * 16 + g * 4 + r;       // token t
        int b = row >> 11, s = row & (S - 1);
#pragma unroll
        for (int ni = 0; ni < 2; ni++) {
          int col = n0 + wid * 32 + ni * 16 + c;
          float val = acc[mi][ni][r];
          if (!ropeTile) {
            int h = col >> 4, cq = col & 15;
            bf16* qrow = Qp + (size_t)((b * 16 + h) * 2048 + s) * 96;
            qrow[64 + cq] = (bf16)(val * KSC);
            qrow[80 + cq] = (bf16)0.f;
          } else {
            int colr = col - 256;
            int h = colr >> 6, jj = colr & 63, j = jj >> 1;
            int pos = pos_ids[row];
            float cf = cos_t[pos * 32 + j], sf = sin_t[pos * 32 + j];
            float other = __shfl_xor(val, 1);
            bf16* qrow = Qp + (size_t)((b * 16 + h) * 2048 + s) * 96;
            if ((c & 1) == 0) {
              qrow[j] = (bf16)((val * cf - other * sf) * KSC);
            } else {
              qrow[32 + j] = (bf16)((val * cf + other * sf) * KSC);
            }
          }
        }
      }
  }
}

// ---------------- absorbed flash attention, single-Kls reg-staged, 2 blocks/CU ----------------
__global__ __launch_bounds__(512, 4) void attn_kernel(
    const bf16* __restrict__ Qp, const bf16* __restrict__ KcG,
    const bf16* __restrict__ cTG, bf16* __restrict__ OC) {
  __shared__ bf16 Kls[128 * 128];     // 32KB
  __shared__ bf16 Cls[2][16 * 128];   // 4KB x2
  __shared__ bf16 Pls[8][16 * 128];   // 4KB per wave

  int lin = blockIdx.x;               // 0..511
  int v = lin >> 8, u = lin & 255;
  int qt = v ? (u >> 1) : (127 - (u >> 1));
  int hg = u & 1, b = v;
  int q0 = qt * 16;
  int nt = qt / 8 + 1;
  int tid = threadIdx.x;
  int w = tid >> 6, lane = tid & 63;
  int g = lane >> 4, cc = lane & 15;
  int h = hg * 8 + w;
  char* pbase = reinterpret_cast<char*>(&Pls[w][0]);

  bf16x8 kst[4];
  auto load_k = [&](int k0) {
#pragma unroll
    for (int i = 0; i < 4; i++) {
      int id = w * 4 + i;
      int key = id * 4 + (lane >> 4);
      int sg = (lane & 15) ^ ((id >> 1) & 15);
      kst[i] = *reinterpret_cast<const bf16x8*>(
          KcG + (((size_t)(b * S + k0 + key)) << 7) + sg * 8);
    }
  };
  auto write_k = [&]() {
#pragma unroll
    for (int i = 0; i < 4; i++) {
      int id = w * 4 + i;
      *reinterpret_cast<bf16x8*>(&Kls[(id * 64 + lane) * 8]) = kst[i];
    }
  };
  auto stage_c = [&](int k0, int buf) {
    if (w >= 4) {
      int c = (w - 4) * 4 + (lane >> 4);
      int sg = (lane & 15) ^ c;
      gload_lds16(cTG + (size_t)(b * 16 + c) * S + k0 + sg * 8,
                  &Cls[buf][(w - 4) * 512]);
    }
  };

  bf16x8 aq[3];
  const bf16* qp = Qp + (size_t)((b * 16 + h) * 2048 + q0 + cc) * 96;
#pragma unroll
  for (int kk = 0; kk < 3; kk++)
    aq[kk] = *reinterpret_cast<const bf16x8*>(qp + kk * 32 + g * 8);

  stage_c(0, 0);
  __builtin_amdgcn_sched_barrier(0);
  load_k(0);
  VMWAIT0;
  write_k();
  if (nt > 1) {
    stage_c(128, 1);
    __builtin_amdgcn_sched_barrier(0);
    load_k(128);
  }
  LGWAIT0;
  __builtin_amdgcn_s_barrier();
  __builtin_amdgcn_sched_barrier(0);

  bf16x8 ones;
#pragma unroll
  for (int j = 0; j < 8; j++) ones[j] = (bf16)1.f;

  f32x4 oc = {}, ls = {};

#pragma unroll 1
  for (int kt = 0; kt < nt; kt++) {
    int cur = kt & 1;
    int k0 = kt * 128;
    f32x4 sacc[8] = {};
    __builtin_amdgcn_s_setprio(1);
#pragma unroll
    for (int kk = 0; kk < 3; kk++)
#pragma unroll
      for (int ntb = 0; ntb < 8; ntb++) {
        int key = cc * 8 + ntb;
        bf16x8 bk = *reinterpret_cast<const bf16x8*>(
            &Kls[(key * 16 + ((kk * 4 + g) ^ cc)) * 8]);
        sacc[ntb] = __builtin_amdgcn_mfma_f32_16x16x32_bf16(aq[kk], bk, sacc[ntb], 0, 0, 0);
      }
    __builtin_amdgcn_s_setprio(0);

    bool diag = (kt == nt - 1);
#pragma unroll
    for (int r = 0; r < 4; r++) {
      bf16x8 pk;
#pragma unroll
      for (int ntb = 0; ntb < 8; ntb++) {
        float x = sacc[ntb][r];
        if (diag) {
          int qr = q0 + g * 4 + r, kc = k0 + cc * 8 + ntb;
          if (kc > qr) x = -1e30f;
        }
        pk[ntb] = (bf16)__builtin_amdgcn_exp2f(x);
      }
      int q = g * 4 + r;
      *reinterpret_cast<bf16x8*>(pbase + (q * 16 + (cc ^ (q & 7))) * 16) = pk;
    }
    LGWAIT0;
    __builtin_amdgcn_s_setprio(1);
#pragma unroll
    for (int kk2 = 0; kk2 < 4; kk2++) {
      bf16x8 pa = *reinterpret_cast<const bf16x8*>(
          pbase + (cc * 16 + ((kk2 * 4 + g) ^ (cc & 7))) * 16);
      bf16x8 bv = *reinterpret_cast<const bf16x8*>(
          &Cls[cur][(cc * 16 + ((kk2 * 4 + g) ^ cc)) * 8]);
      oc = __builtin_amdgcn_mfma_f32_16x16x32_bf16(pa, bv, oc, 0, 0, 0);
      ls = __builtin_amdgcn_mfma_f32_16x16x32_bf16(pa, ones, ls, 0, 0, 0);
    }
    __builtin_amdgcn_s_setprio(0);

    if (kt + 1 < nt) {
      __builtin_amdgcn_s_barrier();
      __builtin_amdgcn_sched_barrier(0);
      VMWAIT0;
      write_k();
      if (kt + 2 < nt) {
        stage_c((kt + 2) * 128, cur);
        __builtin_amdgcn_sched_barrier(0);
        load_k((kt + 2) * 128);
      }
      LGWAIT0;
      __builtin_amdgcn_s_barrier();
      __builtin_amdgcn_sched_barrier(0);
    }
  }

#pragma unroll
  for (int r = 0; r < 4; r++) {
    size_t t = (size_t)b * S + q0 + g * 4 + r;
    OC[t * 256 + h * 16 + cc] = (bf16)(oc[r] / ls[r]);
  }
}

// ---------------- host ----------------
extern "C" void kernel_launch(void* const* d_in, const int* in_sizes, int n_in,
                              void* d_out, int out_size, void* d_ws, size_t ws_size,
                              hipStream_t stream) {
  const float* inputs    = (const float*)d_in[0];
  const int*   pos_ids   = (const int*)d_in[1];
  const float* Wq_down   = (const float*)d_in[3];
  const float* q_norm_w  = (const float*)d_in[4];
  const float* Wq_up     = (const float*)d_in[5];
  const float* Wkv_down  = (const float*)d_in[6];
  const float* kv_norm_w = (const float*)d_in[7];
  const float* Wkv_up    = (const float*)d_in[8];
  const float* Wout      = (const float*)d_in[9];
  float* out = (float*)d_out;

  char* ws = (char*)d_ws;
  size_t off = 0;
  auto alloc = [&](size_t bytes) -> void* {
    void* p = ws + off;
    off += (bytes + 255) & ~(size_t)255;
    return p;
  };

  bf16*  in_bf = (bf16*)alloc((size_t)T * D * 2);
  bf16*  WdT   = (bf16*)alloc((size_t)NDNP * D * 2);
  bf16*  WqxT  = (bf16*)alloc((size_t)NQX * DC_Q * 2);
  bf16*  W2T   = (bf16*)alloc((size_t)D * 256 * 2);
  float* cqkv  = (float*)alloc((size_t)T * NDNP * 4);
  bf16*  cqn   = (bf16*)alloc((size_t)T * DC_Q * 2);
  bf16*  KcG   = (bf16*)alloc((size_t)T * 128 * 2);
  bf16*  cTG   = (bf16*)alloc((size_t)B * 16 * S * 2);
  bf16*  Qp    = (bf16*)alloc((size_t)B * H * S * 96 * 2);
  bf16*  OC    = (bf16*)alloc((size_t)T * H * 16 * 2);
  float* cos_t = (float*)alloc((size_t)S * 32 * 4);
  float* sin_t = (float*)alloc((size_t)S * 32 * 4);

  prologue_kernel<<<4016, 256, 0, stream>>>(
      inputs, Wq_down, Wq_up, Wkv_down, Wkv_up, Wout,
      in_bf, WdT, WqxT, W2T, cos_t, sin_t);

  gemm_bt_kernel<float, 0><<<dim3(NDNP / 128, T / 64), 256, 0, stream>>>(
      in_bf, WdT, cqkv, T, NDNP, D);
  norm_kv_kernel<<<T / 4, 256, 0, stream>>>(
      cqkv, q_norm_w, kv_norm_w, pos_ids, cos_t, sin_t, cqn, KcG, cTG);
  gemm_bt_kernel<bf16, 1><<<dim3(NQX / 128, T / 64), 256, 0, stream>>>(
      cqn, WqxT, (bf16*)nullptr, T, NQX, DC_Q, pos_ids, cos_t, sin_t, Qp);
  attn_kernel<<<512, 512, 0, stream>>>(Qp, KcG, cTG, OC);
  gemm_bt_kernel<float, 0><<<dim3(D / 128, T / 64), 256, 0, stream>>>(
      OC, W2T, out, T, D, 256);
}

// Round 19
// 128.386 us; speedup vs baseline: 1.2993x; 1.0365x over previous
//
#include <hip/hip_runtime.h>

typedef __bf16 bf16;
typedef __bf16 bf16x8 __attribute__((ext_vector_type(8)));
typedef __bf16 bf16x4 __attribute__((ext_vector_type(4)));
typedef float f32x4 __attribute__((ext_vector_type(4)));

constexpr int D = 2048, H = 16, DPH = 128, DR = 64, DC_KV = 16, DC_Q = 512;
constexpr int QHD = 192, MEG = 256, B = 2, S = 2048;
constexpr int T = B * S;
constexpr int NDNP = 640;   // fused down-proj width (512 q + 80 kv), padded to x128
constexpr int NQX = 1280;   // q gemm width: 256 absorbed qc + 1024 rope
constexpr float EPS = 1e-7f;
constexpr float KSC = 0.104124247f;  // (1/sqrt(192)) * log2(e), folded into Qp

static __device__ __forceinline__ bf16x8 zero8() {
  bf16x8 v;
#pragma unroll
  for (int j = 0; j < 8; j++) v[j] = (bf16)0.f;
  return v;
}

static __device__ __forceinline__ void gload_lds16(const bf16* g, bf16* l) {
  __builtin_amdgcn_global_load_lds(
      (const __attribute__((address_space(1))) unsigned int*)g,
      (__attribute__((address_space(3))) unsigned int*)l, 16, 0, 0);
}

#define LGWAIT0 do { asm volatile("s_waitcnt lgkmcnt(0)" ::: "memory"); __builtin_amdgcn_sched_barrier(0); } while (0)
#define VMWAIT0 do { asm volatile("s_waitcnt vmcnt(0)" ::: "memory"); __builtin_amdgcn_sched_barrier(0); } while (0)

// ================= mega prologue: all input-independent prep in ONE launch =================
// Latency-chain sections get LOW block ids (start first); the massively parallel cast goes
// LAST so it overlaps/back-fills the prep chains (fixes the serial tail -> 24% occupancy).
// All write regions pairwise DISJOINT (no inter-block ordering needed):
// blocks [0,32)        : prep_w3 -> WqxT rows [0,256)    (256 thr, v-loop unroll 8)
// blocks [32,160)      : prep_w2 -> W2T                  (256 thr, v-loop unroll 8)
// blocks [160,288)     : prep_wrope -> WqxT rows [256,1280)
// blocks [288,1312)    : transpose Wq_down -> WdT rows [0,512)
// blocks [1312,1504)   : transpose Wkv_down -> WdT rows [512,592)
// blocks [1504,1552)   : zero WdT pad rows [592,640)
// blocks [1552,1808)   : rope table (f32, matches f32 jnp reference)
// blocks [1808,2832)   : cast inputs f32 -> in_bf (8 float4/thread, batched loads)
__global__ __launch_bounds__(256) void prologue_kernel(
    const float* __restrict__ inputs, const float* __restrict__ Wq_down,
    const float* __restrict__ Wq_up, const float* __restrict__ Wkv_down,
    const float* __restrict__ Wkv_up, const float* __restrict__ Wout,
    bf16* __restrict__ in_bf, bf16* __restrict__ WdT, bf16* __restrict__ WqxT,
    bf16* __restrict__ W2T, float* __restrict__ cos_t, float* __restrict__ sin_t) {
  __shared__ float smem[64 * 65];
  int bid = blockIdx.x;
  int tid = threadIdx.x;

  if (bid < 32) {                         // ---- prep_w3 (all 256 threads) ----
    int h = bid >> 1, k0 = (bid & 1) * 256;
    float (*wk)[16] = (float(*)[16])smem;
#pragma unroll
    for (int e = tid; e < 2048; e += 256) {
      int v = e >> 4, c = e & 15;
      wk[v][c] = Wkv_up[(size_t)c * (H * MEG) + h * MEG + v];
    }
    __syncthreads();
    int k = k0 + tid;
    float acc[16] = {};
#pragma unroll 8
    for (int v = 0; v < 128; v++) {
      float wq = Wq_up[(size_t)k * (H * QHD) + h * QHD + v];
#pragma unroll
      for (int c = 0; c < 16; c++) acc[c] += wk[v][c] * wq;
    }
#pragma unroll
    for (int c = 0; c < 16; c++)
      WqxT[(size_t)(h * 16 + c) * DC_Q + k] = (bf16)acc[c];
  } else if (bid < 160) {                 // ---- prep_w2 (all 256 threads) ----
    int lb = bid - 32;
    int h = lb >> 3, d0 = (lb & 7) * 256;
    float (*wv)[16] = (float(*)[16])smem;
#pragma unroll
    for (int e = tid; e < 2048; e += 256) {
      int v = e >> 4, c = e & 15;
      wv[v][c] = Wkv_up[(size_t)c * (H * MEG) + h * MEG + 128 + v];
    }
    __syncthreads();
    int d = d0 + tid;
    float acc[16] = {};
#pragma unroll 8
    for (int v = 0; v < 128; v++) {
      float wo = Wout[(size_t)(h * 128 + v) * D + d];
#pragma unroll
      for (int c = 0; c < 16; c++) acc[c] += wv[v][c] * wo;
    }
    bf16x8 o0, o1;
#pragma unroll
    for (int c = 0; c < 8; c++) { o0[c] = (bf16)acc[c]; o1[c] = (bf16)acc[8 + c]; }
    *reinterpret_cast<bf16x8*>(&W2T[(size_t)d * 256 + h * 16]) = o0;
    *reinterpret_cast<bf16x8*>(&W2T[(size_t)d * 256 + h * 16 + 8]) = o1;
  } else if (bid < 288) {                 // ---- prep_wrope ----
    int lb = bid - 160;
    int h = lb >> 3, k0 = (lb & 7) * 64;
    float (*tile)[65] = (float(*)[65])smem;
#pragma unroll
    for (int p = 0; p < 16; p++) {
      int kk = p * 4 + (tid >> 6), j = tid & 63;
      tile[kk][j] = Wq_up[(size_t)(k0 + kk) * (H * QHD) + h * QHD + 128 + j];
    }
    __syncthreads();
#pragma unroll
    for (int p = 0; p < 16; p++) {
      int n = p * 4 + (tid >> 6), k = tid & 63;
      WqxT[(size_t)(256 + h * 64 + n) * DC_Q + k0 + k] = (bf16)tile[k][n];
    }
  } else if (bid < 1504) {                // ---- transposes ----
    const float* src; bf16* dst; int K, N, k0, n0;
    if (bid < 1312) {
      int lb = bid - 288;
      src = Wq_down; dst = WdT; K = D; N = DC_Q;
      k0 = (lb >> 4) * 32; n0 = (lb & 15) * 32;
    } else {
      int lb = bid - 1312;
      src = Wkv_down; dst = WdT + (size_t)DC_Q * D; K = D; N = 80;
      k0 = (lb / 3) * 32; n0 = (lb % 3) * 32;
    }
    float (*tile)[33] = (float(*)[33])smem;
#pragma unroll
    for (int e = tid; e < 1024; e += 256) {
      int i = e >> 5, j = e & 31;
      int k = k0 + i, n = n0 + j;
      tile[i][j] = (k < K && n < N) ? src[(size_t)k * N + n] : 0.f;
    }
    __syncthreads();
#pragma unroll
    for (int e = tid; e < 1024; e += 256) {
      int jj = e >> 5, ii = e & 31;
      int n = n0 + jj, k = k0 + ii;
      if (k < K && n < N) dst[(size_t)n * D + k] = (bf16)tile[ii][jj];
    }
  } else if (bid < 1552) {                // ---- zero WdT pad rows only ----
    size_t i = (size_t)592 * D + ((size_t)(bid - 1504) * 256 + tid) * 8;
    *reinterpret_cast<bf16x8*>(WdT + i) = zero8();
  } else if (bid < 1808) {                // ---- rope table (f32) ----
    int i = (bid - 1552) * 256 + tid;     // over S*32
    int pos = i >> 5, j = i & 31;
    float invf = 1.0f / powf(10000.0f, (float)(2 * j) / 64.0f);
    float a = (float)pos * invf;
    cos_t[i] = cosf(a);
    sin_t[i] = sinf(a);
  } else {                                // ---- cast (8 rounds, batched loads) ----
    int gid = (bid - 1808) * 256 + tid;   // float4 index, 262144 per round
    float4 v[8];
#pragma unroll
    for (int k = 0; k < 8; k++)
      v[k] = *reinterpret_cast<const float4*>(inputs + ((size_t)(gid + k * 262144)) * 4);
#pragma unroll
    for (int k = 0; k < 8; k++) {
      bf16x4 o;
      o[0] = (bf16)v[k].x; o[1] = (bf16)v[k].y; o[2] = (bf16)v[k].z; o[3] = (bf16)v[k].w;
      *reinterpret_cast<bf16x4*>(in_bf + ((size_t)(gid + k * 262144)) * 4) = o;
    }
  }
}

// ======== merged rmsnorm(q) + kv prep: 1 wave per token ========
__global__ __launch_bounds__(256) void norm_kv_kernel(
    const float* __restrict__ cqkv, const float* __restrict__ qw,
    const float* __restrict__ kvw, const int* __restrict__ pos_ids,
    const float* __restrict__ cos_t, const float* __restrict__ sin_t,
    bf16* __restrict__ cqn, bf16* __restrict__ KcG, bf16* __restrict__ cTG) {
  int w = threadIdx.x >> 6, lane = threadIdx.x & 63;
  int t = blockIdx.x * 4 + w;
  int b = t >> 11, s = t & (S - 1);
  const float* x = cqkv + (size_t)t * NDNP;
  // ---- q rmsnorm over [0,512) ----
  float4 v0 = *reinterpret_cast<const float4*>(x + lane * 8);
  float4 v1 = *reinterpret_cast<const float4*>(x + lane * 8 + 4);
  float ss = v0.x * v0.x + v0.y * v0.y + v0.z * v0.z + v0.w * v0.w +
             v1.x * v1.x + v1.y * v1.y + v1.z * v1.z + v1.w * v1.w;
#pragma unroll
  for (int off = 32; off; off >>= 1) ss += __shfl_xor(ss, off);
  float r = rsqrtf(ss / (float)DC_Q + EPS);
  const float* wp = qw + lane * 8;
  float vv[8] = {v0.x, v0.y, v0.z, v0.w, v1.x, v1.y, v1.z, v1.w};
  bf16x8 o;
#pragma unroll
  for (int j = 0; j < 8; j++) o[j] = (bf16)(vv[j] * r * wp[j]);
  *reinterpret_cast<bf16x8*>(cqn + (size_t)t * DC_Q + lane * 8) = o;
  // ---- kv prep over [512,592) ----
  const float* xk = x + DC_Q;
  float vk = (lane < 16) ? xk[lane] : 0.f;
  float sk = vk * vk;
#pragma unroll
  for (int off = 1; off < 16; off <<= 1) sk += __shfl_xor(sk, off);
  float rk = rsqrtf(sk / 16.f + EPS);
  bf16* krow = KcG + ((size_t)t << 7);
  if (lane < 16) {
    bf16 cn = (bf16)(vk * rk * kvw[lane]);
    krow[64 + lane] = cn;
    cTG[(size_t)(b * 16 + lane) * S + s] = cn;
  } else {
    krow[64 + lane] = (bf16)0.f;   // dims 80..127 zero
  }
  if (lane < 32) {
    int j = lane;
    int pos = pos_ids[t];
    float cf = cos_t[pos * 32 + j], sf = sin_t[pos * 32 + j];
    float x0 = xk[16 + 2 * j], x1 = xk[16 + 2 * j + 1];
    krow[j]      = (bf16)(x0 * cf - x1 * sf);
    krow[32 + j] = (bf16)(x1 * cf + x0 * sf);
  }
}

// ---------------- bf16 MFMA GEMM, 64x128 tile, dbuf + counted vmcnt ----------------
// EPI 0: plain C write. EPI 1: q-path epilogue -> writes Qp (RoPE via lane-pair shfl,
// KSC fold); qc tiles (n0<256) write Qp[64+c] and zero [80+c].
template <typename OutT, int EPI>
__global__ __launch_bounds__(256) void gemm_bt_kernel(
    const bf16* __restrict__ A, const bf16* __restrict__ Bt,
    OutT* __restrict__ C, int M, int N, int K,
    const int* __restrict__ pos_ids = nullptr,
    const float* __restrict__ cos_t = nullptr,
    const float* __restrict__ sin_t = nullptr,
    bf16* __restrict__ Qp = nullptr) {
  __shared__ bf16 As[2][64 * 64];
  __shared__ bf16 Bs[2][128 * 64];
  int tid = threadIdx.x;
  int wid = tid >> 6, lane = tid & 63;
  int g = lane >> 4, c = lane & 15;
  int nbx = gridDim.x;                 // N / 128
  int lin = blockIdx.y * nbx + blockIdx.x;
  int cpx = (nbx * gridDim.y) >> 3;    // grid % 8 == 0 for all uses
  int swz = (lin & 7) * cpx + (lin >> 3);
  int m0 = (swz / nbx) * 64, n0 = (swz % nbx) * 128;
  int lrow8 = tid >> 3, lslot = tid & 7;

  auto stage = [&](int kt, int buf) {
    int k0 = kt << 6;
#pragma unroll
    for (int r = 0; r < 2; r++) {
      int row = r * 32 + lrow8;
      int sslot = lslot ^ (row & 7);
      gload_lds16(A + (size_t)(m0 + row) * K + k0 + sslot * 8, &As[buf][row * 64 + lslot * 8]);
    }
#pragma unroll
    for (int r = 0; r < 4; r++) {
      int row = r * 32 + lrow8;
      int sslot = lslot ^ (row & 7);
      gload_lds16(Bt + (size_t)(n0 + row) * K + k0 + sslot * 8, &Bs[buf][row * 64 + lslot * 8]);
    }
  };

  f32x4 acc[4][2] = {};
  int nk = K >> 6;
  stage(0, 0);
  __builtin_amdgcn_sched_barrier(0);
  for (int kt = 0; kt < nk; kt++) {
    int cur = kt & 1;
    __builtin_amdgcn_s_barrier();
    __builtin_amdgcn_sched_barrier(0);
    if (kt + 1 < nk) {
      stage(kt + 1, cur ^ 1);
      asm volatile("s_waitcnt vmcnt(6)" ::: "memory");
    } else {
      asm volatile("s_waitcnt vmcnt(0)" ::: "memory");
    }
    __builtin_amdgcn_sched_barrier(0);
    __builtin_amdgcn_s_barrier();
    __builtin_amdgcn_sched_barrier(0);
#pragma unroll
    for (int kk = 0; kk < 2; kk++) {
      bf16x8 af[4], bfr[2];
#pragma unroll
      for (int mi = 0; mi < 4; mi++) {
        int row = mi * 16 + c;
        int sl = (kk * 4 + g) ^ (row & 7);
        af[mi] = *reinterpret_cast<const bf16x8*>(&As[cur][row * 64 + sl * 8]);
      }
#pragma unroll
      for (int ni = 0; ni < 2; ni++) {
        int row = wid * 32 + ni * 16 + c;
        int sl = (kk * 4 + g) ^ (row & 7);
        bfr[ni] = *reinterpret_cast<const bf16x8*>(&Bs[cur][row * 64 + sl * 8]);
      }
#pragma unroll
      for (int mi = 0; mi < 4; mi++)
#pragma unroll
        for (int ni = 0; ni < 2; ni++)
          acc[mi][ni] = __builtin_amdgcn_mfma_f32_16x16x32_bf16(af[mi], bfr[ni], acc[mi][ni], 0, 0, 0);
    }
  }

  if constexpr (EPI == 0) {
#pragma unroll
    for (int mi = 0; mi < 4; mi++)
#pragma unroll
      for (int ni = 0; ni < 2; ni++)
#pragma unroll
        for (int r = 0; r < 4; r++) {
          int row = m0 + mi * 16 + g * 4 + r;
          int col = n0 + wid * 32 + ni * 16 + c;
          C[(size_t)row * N + col] = (OutT)acc[mi][ni][r];
        }
  } else {
    // q-path epilogue: write absorbed Q directly
    bool ropeTile = (n0 >= 256);
#pragma unroll
    for (int mi = 0; mi < 4; mi++)
#pragma unroll
      for (int r = 0; r < 4; r++) {
        int row = m0 + mi * 16 + g * 4 + r;       // token t
        int b = row >> 11, s = row & (S - 1);
#pragma unroll
        for (int ni = 0; ni < 2; ni++) {
          int col = n0 + wid * 32 + ni * 16 + c;
          float val = acc[mi][ni][r];
          if (!ropeTile) {
            int h = col >> 4, cq = col & 15;
            bf16* qrow = Qp + (size_t)((b * 16 + h) * 2048 + s) * 96;
            qrow[64 + cq] = (bf16)(val * KSC);
            qrow[80 + cq] = (bf16)0.f;
          } else {
            int colr = col - 256;
            int h = colr >> 6, jj = colr & 63, j = jj >> 1;
            int pos = pos_ids[row];
            float cf = cos_t[pos * 32 + j], sf = sin_t[pos * 32 + j];
            float other = __shfl_xor(val, 1);
            bf16* qrow = Qp + (size_t)((b * 16 + h) * 2048 + s) * 96;
            if ((c & 1) == 0) {
              qrow[j] = (bf16)((val * cf - other * sf) * KSC);
            } else {
              qrow[32 + j] = (bf16)((val * cf + other * sf) * KSC);
            }
          }
        }
      }
  }
}

// ---------------- absorbed flash attention, single-Kls reg-staged, 2 blocks/CU ----------------
__global__ __launch_bounds__(512, 4) void attn_kernel(
    const bf16* __restrict__ Qp, const bf16* __restrict__ KcG,
    const bf16* __restrict__ cTG, bf16* __restrict__ OC) {
  __shared__ bf16 Kls[128 * 128];     // 32KB
  __shared__ bf16 Cls[2][16 * 128];   // 4KB x2
  __shared__ bf16 Pls[8][16 * 128];   // 4KB per wave

  int lin = blockIdx.x;               // 0..511
  int v = lin >> 8, u = lin & 255;
  int qt = v ? (u >> 1) : (127 - (u >> 1));
  int hg = u & 1, b = v;
  int q0 = qt * 16;
  int nt = qt / 8 + 1;
  int tid = threadIdx.x;
  int w = tid >> 6, lane = tid & 63;
  int g = lane >> 4, cc = lane & 15;
  int h = hg * 8 + w;
  char* pbase = reinterpret_cast<char*>(&Pls[w][0]);

  bf16x8 kst[4];
  auto load_k = [&](int k0) {
#pragma unroll
    for (int i = 0; i < 4; i++) {
      int id = w * 4 + i;
      int key = id * 4 + (lane >> 4);
      int sg = (lane & 15) ^ ((id >> 1) & 15);
      kst[i] = *reinterpret_cast<const bf16x8*>(
          KcG + (((size_t)(b * S + k0 + key)) << 7) + sg * 8);
    }
  };
  auto write_k = [&]() {
#pragma unroll
    for (int i = 0; i < 4; i++) {
      int id = w * 4 + i;
      *reinterpret_cast<bf16x8*>(&Kls[(id * 64 + lane) * 8]) = kst[i];
    }
  };
  auto stage_c = [&](int k0, int buf) {
    if (w >= 4) {
      int c = (w - 4) * 4 + (lane >> 4);
      int sg = (lane & 15) ^ c;
      gload_lds16(cTG + (size_t)(b * 16 + c) * S + k0 + sg * 8,
                  &Cls[buf][(w - 4) * 512]);
    }
  };

  bf16x8 aq[3];
  const bf16* qp = Qp + (size_t)((b * 16 + h) * 2048 + q0 + cc) * 96;
#pragma unroll
  for (int kk = 0; kk < 3; kk++)
    aq[kk] = *reinterpret_cast<const bf16x8*>(qp + kk * 32 + g * 8);

  stage_c(0, 0);
  __builtin_amdgcn_sched_barrier(0);
  load_k(0);
  VMWAIT0;
  write_k();
  if (nt > 1) {
    stage_c(128, 1);
    __builtin_amdgcn_sched_barrier(0);
    load_k(128);
  }
  LGWAIT0;
  __builtin_amdgcn_s_barrier();
  __builtin_amdgcn_sched_barrier(0);

  bf16x8 ones;
#pragma unroll
  for (int j = 0; j < 8; j++) ones[j] = (bf16)1.f;

  f32x4 oc = {}, ls = {};

#pragma unroll 1
  for (int kt = 0; kt < nt; kt++) {
    int cur = kt & 1;
    int k0 = kt * 128;
    f32x4 sacc[8] = {};
    __builtin_amdgcn_s_setprio(1);
#pragma unroll
    for (int kk = 0; kk < 3; kk++)
#pragma unroll
      for (int ntb = 0; ntb < 8; ntb++) {
        int key = cc * 8 + ntb;
        bf16x8 bk = *reinterpret_cast<const bf16x8*>(
            &Kls[(key * 16 + ((kk * 4 + g) ^ cc)) * 8]);
        sacc[ntb] = __builtin_amdgcn_mfma_f32_16x16x32_bf16(aq[kk], bk, sacc[ntb], 0, 0, 0);
      }
    __builtin_amdgcn_s_setprio(0);

    bool diag = (kt == nt - 1);
#pragma unroll
    for (int r = 0; r < 4; r++) {
      bf16x8 pk;
#pragma unroll
      for (int ntb = 0; ntb < 8; ntb++) {
        float x = sacc[ntb][r];
        if (diag) {
          int qr = q0 + g * 4 + r, kc = k0 + cc * 8 + ntb;
          if (kc > qr) x = -1e30f;
        }
        pk[ntb] = (bf16)__builtin_amdgcn_exp2f(x);
      }
      int q = g * 4 + r;
      *reinterpret_cast<bf16x8*>(pbase + (q * 16 + (cc ^ (q & 7))) * 16) = pk;
    }
    LGWAIT0;
    __builtin_amdgcn_s_setprio(1);
#pragma unroll
    for (int kk2 = 0; kk2 < 4; kk2++) {
      bf16x8 pa = *reinterpret_cast<const bf16x8*>(
          pbase + (cc * 16 + ((kk2 * 4 + g) ^ (cc & 7))) * 16);
      bf16x8 bv = *reinterpret_cast<const bf16x8*>(
          &Cls[cur][(cc * 16 + ((kk2 * 4 + g) ^ cc)) * 8]);
      oc = __builtin_amdgcn_mfma_f32_16x16x32_bf16(pa, bv, oc, 0, 0, 0);
      ls = __builtin_amdgcn_mfma_f32_16x16x32_bf16(pa, ones, ls, 0, 0, 0);
    }
    __builtin_amdgcn_s_setprio(0);

    if (kt + 1 < nt) {
      __builtin_amdgcn_s_barrier();
      __builtin_amdgcn_sched_barrier(0);
      VMWAIT0;
      write_k();
      if (kt + 2 < nt) {
        stage_c((kt + 2) * 128, cur);
        __builtin_amdgcn_sched_barrier(0);
        load_k((kt + 2) * 128);
      }
      LGWAIT0;
      __builtin_amdgcn_s_barrier();
      __builtin_amdgcn_sched_barrier(0);
    }
  }

#pragma unroll
  for (int r = 0; r < 4; r++) {
    size_t t = (size_t)b * S + q0 + g * 4 + r;
    OC[t * 256 + h * 16 + cc] = (bf16)(oc[r] / ls[r]);
  }
}

// ---------------- host ----------------
extern "C" void kernel_launch(void* const* d_in, const int* in_sizes, int n_in,
                              void* d_out, int out_size, void* d_ws, size_t ws_size,
                              hipStream_t stream) {
  const float* inputs    = (const float*)d_in[0];
  const int*   pos_ids   = (const int*)d_in[1];
  const float* Wq_down   = (const float*)d_in[3];
  const float* q_norm_w  = (const float*)d_in[4];
  const float* Wq_up     = (const float*)d_in[5];
  const float* Wkv_down  = (const float*)d_in[6];
  const float* kv_norm_w = (const float*)d_in[7];
  const float* Wkv_up    = (const float*)d_in[8];
  const float* Wout      = (const float*)d_in[9];
  float* out = (float*)d_out;

  char* ws = (char*)d_ws;
  size_t off = 0;
  auto alloc = [&](size_t bytes) -> void* {
    void* p = ws + off;
    off += (bytes + 255) & ~(size_t)255;
    return p;
  };

  bf16*  in_bf = (bf16*)alloc((size_t)T * D * 2);
  bf16*  WdT   = (bf16*)alloc((size_t)NDNP * D * 2);
  bf16*  WqxT  = (bf16*)alloc((size_t)NQX * DC_Q * 2);
  bf16*  W2T   = (bf16*)alloc((size_t)D * 256 * 2);
  float* cqkv  = (float*)alloc((size_t)T * NDNP * 4);
  bf16*  cqn   = (bf16*)alloc((size_t)T * DC_Q * 2);
  bf16*  KcG   = (bf16*)alloc((size_t)T * 128 * 2);
  bf16*  cTG   = (bf16*)alloc((size_t)B * 16 * S * 2);
  bf16*  Qp    = (bf16*)alloc((size_t)B * H * S * 96 * 2);
  bf16*  OC    = (bf16*)alloc((size_t)T * H * 16 * 2);
  float* cos_t = (float*)alloc((size_t)S * 32 * 4);
  float* sin_t = (float*)alloc((size_t)S * 32 * 4);

  prologue_kernel<<<2832, 256, 0, stream>>>(
      inputs, Wq_down, Wq_up, Wkv_down, Wkv_up, Wout,
      in_bf, WdT, WqxT, W2T, cos_t, sin_t);

  gemm_bt_kernel<float, 0><<<dim3(NDNP / 128, T / 64), 256, 0, stream>>>(
      in_bf, WdT, cqkv, T, NDNP, D);
  norm_kv_kernel<<<T / 4, 256, 0, stream>>>(
      cqkv, q_norm_w, kv_norm_w, pos_ids, cos_t, sin_t, cqn, KcG, cTG);
  gemm_bt_kernel<bf16, 1><<<dim3(NQX / 128, T / 64), 256, 0, stream>>>(
      cqn, WqxT, (bf16*)nullptr, T, NQX, DC_Q, pos_ids, cos_t, sin_t, Qp);
  attn_kernel<<<512, 512, 0, stream>>>(Qp, KcG, cTG, OC);
  gemm_bt_kernel<float, 0><<<dim3(D / 128, T / 64), 256, 0, stream>>>(
      OC, W2T, out, T, D, 256);
}